// Round 8
// baseline (995.082 us; speedup 1.0000x reference)
//
#include <hip/hip_runtime.h>
#include <math.h>

typedef unsigned short u16;
typedef unsigned int u32;
#define DEVI __device__ __forceinline__

typedef __attribute__((ext_vector_type(8))) short bf16x8;
typedef __attribute__((ext_vector_type(4))) float f32x4;

// problem constants
constexpr int kB = 2, kC = 96, kD = 32, kH = 64, kW = 64;
constexpr int kS = kD * kH * kW;   // 131072 spatial positions per batch
constexpr int kM = kB * kS;        // 262144 total tokens
constexpr float kScale = 0.17677669529663687f;  // 32^-0.5

DEVI u16 f2bf(float f) {           // fp32 -> bf16 round-to-nearest-even
  u32 x = __float_as_uint(f);
  return (u16)((x + 0x7fffu + ((x >> 16) & 1u)) >> 16);
}
DEVI float bf2f(u16 v) { return __uint_as_float(((u32)v) << 16); }
DEVI u32 pack2(float a, float b) { return (u32)f2bf(a) | ((u32)f2bf(b) << 16); }

// ---------------- transpose (B,C,S) <-> (B,S,C) ----------------
__global__ void k_tin(const float* __restrict__ in, float* __restrict__ out) {
  __shared__ float tile[32][33];
  int s0 = blockIdx.x << 5, c0 = blockIdx.y << 5, b = blockIdx.z;
  int tx = threadIdx.x, ty = threadIdx.y;
#pragma unroll
  for (int q = 0; q < 4; q++)
    tile[ty + q * 8][tx] = in[((size_t)(b * kC + c0 + ty + q * 8)) * kS + s0 + tx];
  __syncthreads();
#pragma unroll
  for (int q = 0; q < 4; q++)
    out[((size_t)(b * kS + s0 + ty + q * 8)) * kC + c0 + tx] = tile[tx][ty + q * 8];
}

__global__ void k_tout(const float* __restrict__ in, float* __restrict__ out) {
  __shared__ float tile[32][33];
  int s0 = blockIdx.x << 5, c0 = blockIdx.y << 5, b = blockIdx.z;
  int tx = threadIdx.x, ty = threadIdx.y;
#pragma unroll
  for (int q = 0; q < 4; q++)
    tile[ty + q * 8][tx] = in[((size_t)(b * kS + s0 + ty + q * 8)) * kC + c0 + tx];
  __syncthreads();
#pragma unroll
  for (int q = 0; q < 4; q++)
    out[((size_t)(b * kC + c0 + ty + q * 8)) * kS + s0 + tx] = tile[tx][ty + q * 8];
}

// ---------------- LayerNorm (one wave per 96-channel row) ----------------
// MODE 1: window-partition output order. MODE 2: window-partition of rolled tensor.
template <int MODE>
__global__ __launch_bounds__(256) void k_ln(const float* __restrict__ x,
                                            const float* __restrict__ g,
                                            const float* __restrict__ bt,
                                            u16* __restrict__ out) {
  int row = (blockIdx.x << 2) + (threadIdx.x >> 6);
  int lane = threadIdx.x & 63;
  int widx = row >> 6, n = row & 63;
  int ww = widx & 15, wh = (widx >> 4) & 15, wd = (widx >> 8) & 7, bb = widx >> 11;
  int lw = n & 3, lh = (n >> 2) & 3, ld = n >> 4;
  int d = wd * 4 + ld, h = wh * 4 + lh, w = ww * 4 + lw;
  if (MODE == 2) { d = (d + 2) & 31; h = (h + 2) & 63; w = (w + 2) & 63; }
  int src = ((bb * kD + d) * kH + h) * kW + w;
  const float* xr = x + (size_t)src * kC;
  float a0 = xr[lane];
  float a1 = (lane < 32) ? xr[64 + lane] : 0.f;
  float sum = a0 + a1;
#pragma unroll
  for (int m = 32; m; m >>= 1) sum += __shfl_xor(sum, m);
  float mean = sum * (1.f / 96.f);
  float d0 = a0 - mean, d1 = (lane < 32) ? a1 - mean : 0.f;
  float vs = d0 * d0 + d1 * d1;
#pragma unroll
  for (int m = 32; m; m >>= 1) vs += __shfl_xor(vs, m);
  float rstd = rsqrtf(vs * (1.f / 96.f) + 1e-5f);
  u16* orow = out + (size_t)row * kC;
  orow[lane] = f2bf(d0 * rstd * g[lane] + bt[lane]);
  if (lane < 32) orow[64 + lane] = f2bf(d1 * rstd * g[64 + lane] + bt[64 + lane]);
}

// ---------------- proj GEMM + residual + LN2 (fused) ------------------------
// Block = 128 natural rows x 96 cols, 4 waves. A-frags direct from global with
// window->natural gather; W staged to LDS; residual PREFETCHED to registers.
__global__ __launch_bounds__(256, 4) void k_proj(const u16* __restrict__ X,
                                                 const float* __restrict__ Wm,
                                                 const float* __restrict__ bias,
                                                 u16* __restrict__ obf,
                                                 float* __restrict__ oadd,
                                                 const float* __restrict__ lng,
                                                 const float* __restrict__ lnb,
                                                 int shifted) {
  __shared__ __align__(16) u16 Ws[96][104];
  int tid = threadIdx.x;
  int wv = tid >> 6, lane = tid & 63;
  int llo = lane & 15, lhi = lane >> 4;
  int r0 = blockIdx.x << 7;

  // prefetch residual (natural row order) — hides under staging + MFMA
  float resid[2][4][6];
#pragma unroll
  for (int i = 0; i < 2; i++)
#pragma unroll
    for (int rg = 0; rg < 4; rg++) {
      int row = r0 + wv * 32 + i * 16 + lhi * 4 + rg;
#pragma unroll
      for (int j = 0; j < 6; j++)
        resid[i][rg][j] = oadd[(size_t)row * 96 + j * 16 + llo];
    }

  // A-frag loads (window-gathered rows)
  bf16x8 a[2][3];
#pragma unroll
  for (int i = 0; i < 2; i++) {
    int r = r0 + wv * 32 + i * 16 + llo;
    int w = r & 63, h = (r >> 6) & 63, d = (r >> 12) & 31, bb = r >> 17;
    if (shifted) { d = (d + 30) & 31; h = (h + 62) & 63; w = (w + 62) & 63; }
    int widx = ((bb * 8 + (d >> 2)) * 16 + (h >> 2)) * 16 + (w >> 2);
    int rsrc = (widx << 6) + ((d & 3) << 4) + ((h & 3) << 2) + (w & 3);
#pragma unroll
    for (int ks = 0; ks < 3; ks++)
      a[i][ks] = *(const bf16x8*)(X + (size_t)rsrc * 96 + ks * 32 + lhi * 8);
  }

  // stage W (96x96 fp32 -> bf16)
  for (int s = tid; s < 96 * 12; s += 256) {
    int row = s / 12, c8 = s - row * 12;
    const float* src = Wm + (size_t)row * 96 + c8 * 8;
    float4 w0 = *(const float4*)src, w1 = *(const float4*)(src + 4);
    uint4 pk = {pack2(w0.x, w0.y), pack2(w0.z, w0.w),
                pack2(w1.x, w1.y), pack2(w1.z, w1.w)};
    *(uint4*)&Ws[row][c8 * 8] = pk;
  }
  __syncthreads();

  f32x4 acc[2][6];
#pragma unroll
  for (int i = 0; i < 2; i++)
#pragma unroll
    for (int j = 0; j < 6; j++) acc[i][j] = (f32x4){0.f, 0.f, 0.f, 0.f};
#pragma unroll
  for (int ks = 0; ks < 3; ks++) {
    bf16x8 b[6];
#pragma unroll
    for (int j = 0; j < 6; j++)
      b[j] = *(const bf16x8*)&Ws[j * 16 + llo][ks * 32 + lhi * 8];
#pragma unroll
    for (int i = 0; i < 2; i++)
#pragma unroll
      for (int j = 0; j < 6; j++)
        acc[i][j] = __builtin_amdgcn_mfma_f32_16x16x32_bf16(a[i][ks], b[j], acc[i][j], 0, 0, 0);
  }

  // epilogue: +bias +resid -> bx, then LN -> bf16 obf
  float bj[6], gj[6], betaj[6];
#pragma unroll
  for (int j = 0; j < 6; j++) {
    int col = j * 16 + llo;
    bj[j] = bias[col]; gj[j] = lng[col]; betaj[j] = lnb[col];
  }
#pragma unroll
  for (int i = 0; i < 2; i++) {
#pragma unroll
    for (int rg = 0; rg < 4; rg++) {
      int row = r0 + wv * 32 + i * 16 + lhi * 4 + rg;
      float vv[6], sum = 0.f;
#pragma unroll
      for (int j = 0; j < 6; j++) {
        vv[j] = acc[i][j][rg] + bj[j] + resid[i][rg][j];
        sum += vv[j];
      }
#pragma unroll
      for (int m = 1; m <= 8; m <<= 1) sum += __shfl_xor(sum, m);
      float mean = sum * (1.f / 96.f);
      float vs = 0.f;
#pragma unroll
      for (int j = 0; j < 6; j++) { float dd = vv[j] - mean; vs += dd * dd; }
#pragma unroll
      for (int m = 1; m <= 8; m <<= 1) vs += __shfl_xor(vs, m);
      float rstd = rsqrtf(vs * (1.f / 96.f) + 1e-5f);
#pragma unroll
      for (int j = 0; j < 6; j++) {
        int col = j * 16 + llo;
        oadd[(size_t)row * 96 + col] = vv[j];
        obf[(size_t)row * 96 + col] = f2bf((vv[j] - mean) * rstd * gj[j] + betaj[j]);
      }
    }
  }
}

// ---------------- fused MLP: fc1 + GELU + fc2 + residual --------------------
// Block = 64 rows, 4 waves (each 16 rows). Hidden (64x384) lives ONLY in LDS.
// Phase A: 4 chunks of 96 hidden cols: stage W1 chunk, MFMA, GELU -> Hs.
// Phase B: 4 k-chunks: stage W2 chunk, A-frags from Hs, MFMA accumulate.
// Epilogue: + bias + prefetched residual -> bx (fp32).
__global__ __launch_bounds__(256) void k_mlp(const u16* __restrict__ X,
                                             const float* __restrict__ W1,
                                             const float* __restrict__ b1,
                                             const float* __restrict__ W2,
                                             const float* __restrict__ b2,
                                             float* __restrict__ bx) {
  __shared__ __align__(16) u16 Hs[64 * 400];
  __shared__ __align__(16) u16 Ws[96 * 104];
  int tid = threadIdx.x, wv = tid >> 6, lane = tid & 63;
  int llo = lane & 15, lhi = lane >> 4;
  int r0 = blockIdx.x << 6;
  int rowb = wv * 16;

  // prefetch residual — hides under both GEMM phases
  float resid[4][6];
#pragma unroll
  for (int rg = 0; rg < 4; rg++) {
    int row = r0 + rowb + lhi * 4 + rg;
#pragma unroll
    for (int j = 0; j < 6; j++)
      resid[rg][j] = bx[(size_t)row * 96 + j * 16 + llo];
  }

  // X A-frags (LN2 output, natural rows; reused by all 4 fc1 chunks)
  const u16* xr = X + (size_t)(r0 + rowb + llo) * 96;
  bf16x8 ax[3];
#pragma unroll
  for (int ks = 0; ks < 3; ks++) ax[ks] = *(const bf16x8*)(xr + ks * 32 + lhi * 8);

  // ---- phase A: fc1 + GELU -> Hs ----
  for (int c = 0; c < 4; c++) {
    if (c) __syncthreads();
    for (int s = tid; s < 96 * 12; s += 256) {
      int row = s / 12, c8 = s - row * 12;
      const float* src = W1 + (size_t)(c * 96 + row) * 96 + c8 * 8;
      float4 w0 = *(const float4*)src, w1 = *(const float4*)(src + 4);
      uint4 pk = {pack2(w0.x, w0.y), pack2(w0.z, w0.w),
                  pack2(w1.x, w1.y), pack2(w1.z, w1.w)};
      *(uint4*)&Ws[row * 104 + c8 * 8] = pk;
    }
    __syncthreads();
    f32x4 acc[6];
#pragma unroll
    for (int j = 0; j < 6; j++) acc[j] = (f32x4){0.f, 0.f, 0.f, 0.f};
#pragma unroll
    for (int ks = 0; ks < 3; ks++) {
#pragma unroll
      for (int j = 0; j < 6; j++) {
        bf16x8 b = *(const bf16x8*)&Ws[(j * 16 + llo) * 104 + ks * 32 + lhi * 8];
        acc[j] = __builtin_amdgcn_mfma_f32_16x16x32_bf16(ax[ks], b, acc[j], 0, 0, 0);
      }
    }
#pragma unroll
    for (int j = 0; j < 6; j++) {
      int col = c * 96 + j * 16 + llo;
      float bb_ = b1[col];
#pragma unroll
      for (int rg = 0; rg < 4; rg++) {
        float v = acc[j][rg] + bb_;
        Hs[(rowb + lhi * 4 + rg) * 400 + col] =
            f2bf(0.5f * v * (1.f + erff(v * 0.70710678118654752f)));
      }
    }
  }
  __syncthreads();

  // ---- phase B: fc2 (accumulate over 4 hidden k-chunks) ----
  f32x4 acc2[6];
#pragma unroll
  for (int j = 0; j < 6; j++) acc2[j] = (f32x4){0.f, 0.f, 0.f, 0.f};
  for (int kc = 0; kc < 4; kc++) {
    if (kc) __syncthreads();
    for (int s = tid; s < 96 * 12; s += 256) {
      int row = s / 12, c8 = s - row * 12;
      const float* src = W2 + (size_t)row * 384 + kc * 96 + c8 * 8;
      float4 w0 = *(const float4*)src, w1 = *(const float4*)(src + 4);
      uint4 pk = {pack2(w0.x, w0.y), pack2(w0.z, w0.w),
                  pack2(w1.x, w1.y), pack2(w1.z, w1.w)};
      *(uint4*)&Ws[row * 104 + c8 * 8] = pk;
    }
    __syncthreads();
    bf16x8 ah[3];
#pragma unroll
    for (int ks = 0; ks < 3; ks++)
      ah[ks] = *(const bf16x8*)&Hs[(rowb + llo) * 400 + kc * 96 + ks * 32 + lhi * 8];
#pragma unroll
    for (int ks = 0; ks < 3; ks++)
#pragma unroll
      for (int j = 0; j < 6; j++) {
        bf16x8 b = *(const bf16x8*)&Ws[(j * 16 + llo) * 104 + ks * 32 + lhi * 8];
        acc2[j] = __builtin_amdgcn_mfma_f32_16x16x32_bf16(ah[ks], b, acc2[j], 0, 0, 0);
      }
  }

  // epilogue: + bias + residual -> bx
#pragma unroll
  for (int j = 0; j < 6; j++) {
    int col = j * 16 + llo;
    float bb_ = b2[col];
#pragma unroll
    for (int rg = 0; rg < 4; rg++) {
      int row = r0 + rowb + lhi * 4 + rg;
      bx[(size_t)row * 96 + col] = acc2[j][rg] + bb_ + resid[rg][j];
    }
  }
}

// ---------------- fused QKV-GEMM + windowed attention (16 waves) -----------
// One block = 2 windows (128 rows), 1024 threads. GEMM: wave = 16 rows x 48
// cols, A-frags direct from global. Q/K -> LDS row-major; V -> LDS transposed.
// Attention: 12 units (pair,head,qhalf) on waves 0..11; P overlays dead QK.
__global__ __launch_bounds__(1024, 4) void k_qa(const u16* __restrict__ X,
                                                const float* __restrict__ Wq,
                                                const float* __restrict__ bq,
                                                const float* __restrict__ rpb,
                                                u16* __restrict__ out, int shifted) {
  __shared__ __align__(16) char arena[90656];
  u16* QK = (u16*)arena;                 // [128][200]: cols 0..95 Q, 96..191 K
  u16* VT = (u16*)(arena + 51200);       // [pair*3+head][32 d][40]: V^T
  u16* Ws = (u16*)(arena + 66560);       // [96][104]
  float* RP = (float*)(arena + 86528);   // [3][343]

  int tid = threadIdx.x, wv = tid >> 6, lane = tid & 63;
  int llo = lane & 15, lhi = lane >> 4;
  int r0 = blockIdx.x << 7;
  int rowb = (wv >> 1) * 16;             // GEMM row base
  int colb = (wv & 1) * 48;              // GEMM col base

  // rel-pos bias table (region independent of GEMM buffers)
  for (int t = tid; t < 1029; t += 1024) {
    int head = t / 343, idx = t - head * 343;
    RP[t] = rpb[idx * 3 + head];
  }

  // A-fragments for this lane's 16 GEMM rows (shared across Q/K/V chunks)
  const u16* xrow = X + (size_t)(r0 + rowb + llo) * 96;
  bf16x8 a[3];
#pragma unroll
  for (int ks = 0; ks < 3; ks++) a[ks] = *(const bf16x8*)(xrow + ks * 32 + lhi * 8);

  for (int c = 0; c < 3; c++) {
    if (c) __syncthreads();
    for (int s = tid; s < 96 * 12; s += 1024) {
      int row = s / 12, c8 = s - row * 12;
      const float* src = Wq + (size_t)(c * 96 + row) * 96 + c8 * 8;
      float4 w0 = *(const float4*)src, w1 = *(const float4*)(src + 4);
      uint4 pk = {pack2(w0.x, w0.y), pack2(w0.z, w0.w),
                  pack2(w1.x, w1.y), pack2(w1.z, w1.w)};
      *(uint4*)&Ws[row * 104 + c8 * 8] = pk;
    }
    __syncthreads();
    f32x4 acc[3];
#pragma unroll
    for (int j = 0; j < 3; j++) acc[j] = (f32x4){0.f, 0.f, 0.f, 0.f};
#pragma unroll
    for (int ks = 0; ks < 3; ks++) {
#pragma unroll
      for (int j = 0; j < 3; j++) {
        bf16x8 b = *(const bf16x8*)&Ws[(colb + j * 16 + llo) * 104 + ks * 32 + lhi * 8];
        acc[j] = __builtin_amdgcn_mfma_f32_16x16x32_bf16(a[ks], b, acc[j], 0, 0, 0);
      }
    }
    if (c < 2) {  // Q / K -> QK row-major
#pragma unroll
      for (int j = 0; j < 3; j++) {
        int col = colb + j * 16 + llo;
        float bb_ = bq[c * 96 + col];
#pragma unroll
        for (int rg = 0; rg < 4; rg++)
          QK[(rowb + lhi * 4 + rg) * 200 + c * 96 + col] = f2bf(acc[j][rg] + bb_);
      }
    } else {      // V -> VT transposed per (pair, head)
#pragma unroll
      for (int j = 0; j < 3; j++) {
        int dcol = colb + j * 16 + llo;
        float bb_ = bq[192 + dcol];
        int head = dcol >> 5, d = dcol & 31;
#pragma unroll
        for (int rg = 0; rg < 4; rg++) {
          int row = rowb + lhi * 4 + rg;
          VT[(((row >> 6) * 3 + head) * 32 + d) * 40 + (row & 63)] = f2bf(acc[j][rg] + bb_);
        }
      }
    }
  }
  __syncthreads();

  // attention: 12 units = (pair, head, q-half); waves 12..15 idle
  int u = wv;
  bool active = (u < 12);
  int pair = u / 6, rem = u - pair * 6, head = rem >> 1, qh = rem & 1;
  int widx = (blockIdx.x << 1) + pair;
  int ww = widx & 15, wh = (widx >> 4) & 15, wd = (widx >> 8) & 7;
  const float* rp = RP + head * 343;
  const u16* qkw = QK + pair * 64 * 200;
  u16* plw = QK + u * 2112;              // P overlay on dead QK (32 x stride 66)

  f32x4 s[2][4];
  bf16x8 bv[2][2];
  if (active) {
    bf16x8 aq[2], bk[4];
#pragma unroll
    for (int qt2 = 0; qt2 < 2; qt2++)
      aq[qt2] = *(const bf16x8*)&qkw[(qh * 32 + qt2 * 16 + llo) * 200 + head * 32 + lhi * 8];
#pragma unroll
    for (int kt = 0; kt < 4; kt++)
      bk[kt] = *(const bf16x8*)&qkw[(kt * 16 + llo) * 200 + 96 + head * 32 + lhi * 8];
    // V fragments (VT region is not overlaid; load now to hide latency)
    const u16* vtb = VT + (pair * 3 + head) * 32 * 40;
#pragma unroll
    for (int jt = 0; jt < 2; jt++)
#pragma unroll
      for (int ks = 0; ks < 2; ks++)
        bv[jt][ks] = *(const bf16x8*)&vtb[(jt * 16 + llo) * 40 + ks * 32 + lhi * 8];

#pragma unroll
    for (int qt2 = 0; qt2 < 2; qt2++)
#pragma unroll
      for (int kt = 0; kt < 4; kt++)
        s[qt2][kt] = __builtin_amdgcn_mfma_f32_16x16x32_bf16(
            aq[qt2], bk[kt], (f32x4){0.f, 0.f, 0.f, 0.f}, 0, 0, 0);

    int jh = llo >> 2, jw = llo & 3;
    int mi_h = (wh == 15) ? (1 + (lhi >= 2)) : 0;
    int mj_hw = ((wh == 15) ? (1 + (jh >= 2)) : 0) * 3 +
                ((ww == 15) ? (1 + (jw >= 2)) : 0);
#pragma unroll
    for (int qt2 = 0; qt2 < 2; qt2++) {
      int qt = qh * 2 + qt2;
#pragma unroll
      for (int kt = 0; kt < 4; kt++) {
        const float* rb = &rp[(qt - kt + 3) * 49 + (lhi - jh + 3) * 7 + (3 - jw)];
#pragma unroll
        for (int e = 0; e < 4; e++) {
          float val = fmaf(s[qt2][kt][e], kScale, rb[e]);
          if (shifted) {
            int ci = ((wd == 7) ? (1 + (qt >= 2)) : 0) * 9 + mi_h * 3 +
                     ((ww == 15) ? (1 + (e >= 2)) : 0);
            int cj = ((wd == 7) ? (1 + (kt >= 2)) : 0) * 9 + mj_hw;
            if (ci != cj) val -= 100.f;
          }
          s[qt2][kt][e] = val;
        }
      }
    }
    // softmax per row (qt2, e): local max/sum over kt, butterfly over llo
#pragma unroll
    for (int qt2 = 0; qt2 < 2; qt2++) {
      f32x4 m;
#pragma unroll
      for (int e = 0; e < 4; e++)
        m[e] = fmaxf(fmaxf(s[qt2][0][e], s[qt2][1][e]), fmaxf(s[qt2][2][e], s[qt2][3][e]));
#pragma unroll
      for (int msk = 1; msk <= 8; msk <<= 1)
#pragma unroll
        for (int e = 0; e < 4; e++) m[e] = fmaxf(m[e], __shfl_xor(m[e], msk));
      f32x4 sum = (f32x4){0.f, 0.f, 0.f, 0.f};
#pragma unroll
      for (int kt = 0; kt < 4; kt++)
#pragma unroll
        for (int e = 0; e < 4; e++) {
          float p = __expf(s[qt2][kt][e] - m[e]);
          s[qt2][kt][e] = p;
          sum[e] += p;
        }
#pragma unroll
      for (int msk = 1; msk <= 8; msk <<= 1)
#pragma unroll
        for (int e = 0; e < 4; e++) sum[e] += __shfl_xor(sum[e], msk);
#pragma unroll
      for (int e = 0; e < 4; e++) sum[e] = 1.f / sum[e];
#pragma unroll
      for (int kt = 0; kt < 4; kt++)
#pragma unroll
        for (int e = 0; e < 4; e++) s[qt2][kt][e] *= sum[e];
    }
  }
  __syncthreads();  // all QK reads complete -> safe to overlay P
  if (active) {
#pragma unroll
    for (int qt2 = 0; qt2 < 2; qt2++)
#pragma unroll
      for (int kt = 0; kt < 4; kt++)
#pragma unroll
        for (int e = 0; e < 4; e++)
          plw[(qt2 * 16 + lhi * 4 + e) * 66 + kt * 16 + llo] = f2bf(s[qt2][kt][e]);
  }
  __syncthreads();
  if (active) {
    f32x4 o[2][2];
#pragma unroll
    for (int qt2 = 0; qt2 < 2; qt2++) {
      o[qt2][0] = (f32x4){0.f, 0.f, 0.f, 0.f};
      o[qt2][1] = (f32x4){0.f, 0.f, 0.f, 0.f};
#pragma unroll
      for (int ks = 0; ks < 2; ks++) {
        bf16x8 pa = *(const bf16x8*)&plw[(qt2 * 16 + llo) * 66 + ks * 32 + lhi * 8];
        o[qt2][0] = __builtin_amdgcn_mfma_f32_16x16x32_bf16(pa, bv[0][ks], o[qt2][0], 0, 0, 0);
        o[qt2][1] = __builtin_amdgcn_mfma_f32_16x16x32_bf16(pa, bv[1][ks], o[qt2][1], 0, 0, 0);
      }
    }
    u16* ob = out + (size_t)widx * 64 * 96 + head * 32;
#pragma unroll
    for (int qt2 = 0; qt2 < 2; qt2++)
#pragma unroll
      for (int jt = 0; jt < 2; jt++)
#pragma unroll
        for (int e = 0; e < 4; e++)
          ob[(size_t)(qh * 32 + qt2 * 16 + lhi * 4 + e) * 96 + jt * 16 + llo] =
              f2bf(o[qt2][jt][e]);
  }
}

// ---------------- launcher ----------------
extern "C" void kernel_launch(void* const* d_in, const int* in_sizes, int n_in,
                              void* d_out, int out_size, void* d_ws, size_t ws_size,
                              hipStream_t stream) {
  const float* x_in = (const float*)d_in[0];
  const float* n1g = (const float*)d_in[1];
  const float* n1b = (const float*)d_in[2];
  const float* qkvw = (const float*)d_in[3];
  const float* qkvb = (const float*)d_in[4];
  const float* rpb = (const float*)d_in[5];
  const float* projw = (const float*)d_in[6];
  const float* projb = (const float*)d_in[7];
  const float* n2g = (const float*)d_in[8];
  const float* n2b = (const float*)d_in[9];
  const float* fc1w = (const float*)d_in[10];
  const float* fc1b = (const float*)d_in[11];
  const float* fc2w = (const float*)d_in[12];
  const float* fc2b = (const float*)d_in[13];
  float* outp = (float*)d_out;

  // workspace: fp32 master x (100.7 MB) | bf16 small buf (50.3 MB) | bf16 big buf (201.3 MB)
  char* ws = (char*)d_ws;
  float* bx = (float*)ws;
  u16* ba = (u16*)(ws + 100663296);   // LN1 out / LN2 out (bf16)
  u16* bb = (u16*)(ws + 150994944);   // attn out (bf16)

  k_tin<<<dim3(kS / 32, 3, kB), dim3(32, 8), 0, stream>>>(x_in, bx);

  for (int blk = 0; blk < 2; blk++) {
    int sh = blk;  // block 1 is shifted
    if (blk == 0)
      k_ln<1><<<kM / 4, 256, 0, stream>>>(bx, n1g, n1b, ba);
    else
      k_ln<2><<<kM / 4, 256, 0, stream>>>(bx, n1g + 96, n1b + 96, ba);
    k_qa<<<kM / 128, 1024, 0, stream>>>(ba, qkvw + blk * 288 * 96, qkvb + blk * 288,
                                        rpb + blk * 343 * 3, bb, sh);
    // proj + residual + LN2 fused
    k_proj<<<kM / 128, 256, 0, stream>>>(bb, projw + blk * 96 * 96, projb + blk * 96,
                                         ba, bx, n2g + blk * 96, n2b + blk * 96, sh);
    // fc1 + GELU + fc2 + residual fused (hidden never leaves LDS)
    k_mlp<<<kM / 64, 256, 0, stream>>>(ba, fc1w + blk * 384 * 96, fc1b + blk * 384,
                                       fc2w + blk * 96 * 384, fc2b + blk * 96, bx);
  }

  k_tout<<<dim3(kS / 32, 3, kB), dim3(32, 8), 0, stream>>>(bx, outp);
}

// Round 9
// 916.355 us; speedup vs baseline: 1.0859x; 1.0859x over previous
//
#include <hip/hip_runtime.h>
#include <math.h>

typedef unsigned short u16;
typedef unsigned int u32;
#define DEVI __device__ __forceinline__

typedef __attribute__((ext_vector_type(8))) short bf16x8;
typedef __attribute__((ext_vector_type(4))) float f32x4;

// problem constants
constexpr int kB = 2, kC = 96, kD = 32, kH = 64, kW = 64;
constexpr int kS = kD * kH * kW;   // 131072 spatial positions per batch
constexpr int kM = kB * kS;        // 262144 total tokens
constexpr float kScale = 0.17677669529663687f;  // 32^-0.5

DEVI u16 f2bf(float f) {           // fp32 -> bf16 round-to-nearest-even
  u32 x = __float_as_uint(f);
  return (u16)((x + 0x7fffu + ((x >> 16) & 1u)) >> 16);
}
DEVI float bf2f(u16 v) { return __uint_as_float(((u32)v) << 16); }
DEVI u32 pack2(float a, float b) { return (u32)f2bf(a) | ((u32)f2bf(b) << 16); }

// ---------------- transpose (B,C,S) <-> (B,S,C) ----------------
__global__ void k_tin(const float* __restrict__ in, float* __restrict__ out) {
  __shared__ float tile[32][33];
  int s0 = blockIdx.x << 5, c0 = blockIdx.y << 5, b = blockIdx.z;
  int tx = threadIdx.x, ty = threadIdx.y;
#pragma unroll
  for (int q = 0; q < 4; q++)
    tile[ty + q * 8][tx] = in[((size_t)(b * kC + c0 + ty + q * 8)) * kS + s0 + tx];
  __syncthreads();
#pragma unroll
  for (int q = 0; q < 4; q++)
    out[((size_t)(b * kS + s0 + ty + q * 8)) * kC + c0 + tx] = tile[tx][ty + q * 8];
}

__global__ void k_tout(const float* __restrict__ in, float* __restrict__ out) {
  __shared__ float tile[32][33];
  int s0 = blockIdx.x << 5, c0 = blockIdx.y << 5, b = blockIdx.z;
  int tx = threadIdx.x, ty = threadIdx.y;
#pragma unroll
  for (int q = 0; q < 4; q++)
    tile[ty + q * 8][tx] = in[((size_t)(b * kS + s0 + ty + q * 8)) * kC + c0 + tx];
  __syncthreads();
#pragma unroll
  for (int q = 0; q < 4; q++)
    out[((size_t)(b * kC + c0 + ty + q * 8)) * kS + s0 + tx] = tile[tx][ty + q * 8];
}

// ---------------- one-time weight fp32 -> bf16 conversion -------------------
__global__ __launch_bounds__(256) void k_wcvt(const float* __restrict__ q,
                                              const float* __restrict__ p,
                                              const float* __restrict__ f1,
                                              const float* __restrict__ f2,
                                              u16* dq, u16* dp, u16* df1, u16* df2) {
  int a = blockIdx.y;
  const float* sp; u16* dst; int n;
  if (a == 0)      { sp = q;  dst = dq;  n = 2 * 288 * 96; }
  else if (a == 1) { sp = p;  dst = dp;  n = 2 * 96 * 96; }
  else if (a == 2) { sp = f1; dst = df1; n = 2 * 384 * 96; }
  else             { sp = f2; dst = df2; n = 2 * 96 * 384; }
  for (int i = (blockIdx.x * 256 + threadIdx.x) * 4; i < n; i += gridDim.x * 1024) {
    float4 v = *(const float4*)(sp + i);
    *(u32*)(dst + i) = pack2(v.x, v.y);
    *(u32*)(dst + i + 2) = pack2(v.z, v.w);
  }
}

// ---------------- fused LN1 + QKV-GEMM + windowed attention (16 waves) ------
// One block = 2 windows (128 rows), 1024 threads. LN1 computed in-register
// from bx fp32 (window-gathered rows); QKV B-frags direct from global bf16 W
// (no staging, no per-chunk barriers). Q/K -> LDS row-major; V -> transposed.
// Attention: 12 units (pair,head,qhalf) on waves 0..11; P overlays dead QK.
__global__ __launch_bounds__(1024, 4) void k_qa(const float* __restrict__ BX,
                                                const float* __restrict__ g1,
                                                const float* __restrict__ be1,
                                                const u16* __restrict__ Wq,
                                                const float* __restrict__ bq,
                                                const float* __restrict__ rpb,
                                                u16* __restrict__ out, int shifted) {
  __shared__ __align__(16) char arena[70720];
  u16* QK = (u16*)arena;                 // [128][200]: cols 0..95 Q, 96..191 K
  u16* VT = (u16*)(arena + 51200);       // [pair*3+head][32 d][40]: V^T
  float* RP = (float*)(arena + 66560);   // [3][343]

  int tid = threadIdx.x, wv = tid >> 6, lane = tid & 63;
  int llo = lane & 15, lhi = lane >> 4;
  int r0 = blockIdx.x << 7;
  int rowb = (wv >> 1) * 16;             // GEMM row base
  int colb = (wv & 1) * 48;              // GEMM col base

  for (int t = tid; t < 1029; t += 1024) {
    int head = t / 343, idx = t - head * 343;
    RP[t] = rpb[idx * 3 + head];
  }

  // ---- fused LN1: gather x row (window order -> natural), normalize ----
  {
    int r = r0 + rowb + llo;
    int wI = r >> 6, n = r & 63;
    int Xw = wI & 15, Xh = (wI >> 4) & 15, Xd = (wI >> 8) & 7, Xb = wI >> 11;
    int d = Xd * 4 + (n >> 4), h = Xh * 4 + ((n >> 2) & 3), w = Xw * 4 + (n & 3);
    if (shifted) { d = (d + 2) & 31; h = (h + 2) & 63; w = (w + 2) & 63; }
    const float* xr = BX + (size_t)(((Xb * kD + d) * kH + h) * kW + w) * 96;
    float xv[3][8];
#pragma unroll
    for (int ks = 0; ks < 3; ks++) {
      float4 p0 = *(const float4*)(xr + ks * 32 + lhi * 8);
      float4 p1 = *(const float4*)(xr + ks * 32 + lhi * 8 + 4);
      xv[ks][0] = p0.x; xv[ks][1] = p0.y; xv[ks][2] = p0.z; xv[ks][3] = p0.w;
      xv[ks][4] = p1.x; xv[ks][5] = p1.y; xv[ks][6] = p1.z; xv[ks][7] = p1.w;
    }
    float sum = 0.f;
#pragma unroll
    for (int ks = 0; ks < 3; ks++)
#pragma unroll
      for (int e = 0; e < 8; e++) sum += xv[ks][e];
    sum += __shfl_xor(sum, 16); sum += __shfl_xor(sum, 32);
    float mean = sum * (1.f / 96.f);
    float vs = 0.f;
#pragma unroll
    for (int ks = 0; ks < 3; ks++)
#pragma unroll
      for (int e = 0; e < 8; e++) { float dd = xv[ks][e] - mean; vs += dd * dd; }
    vs += __shfl_xor(vs, 16); vs += __shfl_xor(vs, 32);
    float rstd = rsqrtf(vs * (1.f / 96.f) + 1e-5f);
    bf16x8 a[3];
#pragma unroll
    for (int ks = 0; ks < 3; ks++) {
      const float* gp = g1 + ks * 32 + lhi * 8;
      const float* bp = be1 + ks * 32 + lhi * 8;
      float4 g0 = *(const float4*)gp, g4 = *(const float4*)(gp + 4);
      float4 b0 = *(const float4*)bp, b4 = *(const float4*)(bp + 4);
      float gf[8] = {g0.x, g0.y, g0.z, g0.w, g4.x, g4.y, g4.z, g4.w};
      float bf[8] = {b0.x, b0.y, b0.z, b0.w, b4.x, b4.y, b4.z, b4.w};
      bf16x8 t;
#pragma unroll
      for (int e = 0; e < 8; e++)
        t[e] = (short)f2bf((xv[ks][e] - mean) * rstd * gf[e] + bf[e]);
      a[ks] = t;
    }

    // ---- QKV GEMM: B-frags direct from global bf16 W, no barriers ----
    for (int c = 0; c < 3; c++) {
      f32x4 acc[3];
#pragma unroll
      for (int j = 0; j < 3; j++) acc[j] = (f32x4){0.f, 0.f, 0.f, 0.f};
#pragma unroll
      for (int ks = 0; ks < 3; ks++)
#pragma unroll
        for (int j = 0; j < 3; j++) {
          bf16x8 b = *(const bf16x8*)(Wq + (size_t)(c * 96 + colb + j * 16 + llo) * 96 +
                                      ks * 32 + lhi * 8);
          acc[j] = __builtin_amdgcn_mfma_f32_16x16x32_bf16(a[ks], b, acc[j], 0, 0, 0);
        }
      if (c < 2) {  // Q / K -> QK row-major
#pragma unroll
        for (int j = 0; j < 3; j++) {
          int col = colb + j * 16 + llo;
          float bb_ = bq[c * 96 + col];
#pragma unroll
          for (int rg = 0; rg < 4; rg++)
            QK[(rowb + lhi * 4 + rg) * 200 + c * 96 + col] = f2bf(acc[j][rg] + bb_);
        }
      } else {      // V -> VT transposed per (pair, head)
#pragma unroll
        for (int j = 0; j < 3; j++) {
          int dcol = colb + j * 16 + llo;
          float bb_ = bq[192 + dcol];
          int head = dcol >> 5, dd = dcol & 31;
#pragma unroll
          for (int rg = 0; rg < 4; rg++) {
            int row = rowb + lhi * 4 + rg;
            VT[(((row >> 6) * 3 + head) * 32 + dd) * 40 + (row & 63)] = f2bf(acc[j][rg] + bb_);
          }
        }
      }
    }
  }
  __syncthreads();

  // attention: 12 units = (pair, head, q-half); waves 12..15 idle
  int u = wv;
  bool active = (u < 12);
  int pair = u / 6, rem = u - pair * 6, head = rem >> 1, qh = rem & 1;
  int widx = (blockIdx.x << 1) + pair;
  int ww = widx & 15, wh = (widx >> 4) & 15, wd = (widx >> 8) & 7;
  const float* rp = RP + head * 343;
  const u16* qkw = QK + pair * 64 * 200;
  u16* plw = QK + u * 2112;              // P overlay on dead QK (32 x stride 66)

  f32x4 s[2][4];
  bf16x8 bv[2][2];
  if (active) {
    bf16x8 aq[2], bk[4];
#pragma unroll
    for (int qt2 = 0; qt2 < 2; qt2++)
      aq[qt2] = *(const bf16x8*)&qkw[(qh * 32 + qt2 * 16 + llo) * 200 + head * 32 + lhi * 8];
#pragma unroll
    for (int kt = 0; kt < 4; kt++)
      bk[kt] = *(const bf16x8*)&qkw[(kt * 16 + llo) * 200 + 96 + head * 32 + lhi * 8];
    const u16* vtb = VT + (pair * 3 + head) * 32 * 40;
#pragma unroll
    for (int jt = 0; jt < 2; jt++)
#pragma unroll
      for (int ks = 0; ks < 2; ks++)
        bv[jt][ks] = *(const bf16x8*)&vtb[(jt * 16 + llo) * 40 + ks * 32 + lhi * 8];

#pragma unroll
    for (int qt2 = 0; qt2 < 2; qt2++)
#pragma unroll
      for (int kt = 0; kt < 4; kt++)
        s[qt2][kt] = __builtin_amdgcn_mfma_f32_16x16x32_bf16(
            aq[qt2], bk[kt], (f32x4){0.f, 0.f, 0.f, 0.f}, 0, 0, 0);

    int jh = llo >> 2, jw = llo & 3;
    int mi_h = (wh == 15) ? (1 + (lhi >= 2)) : 0;
    int mj_hw = ((wh == 15) ? (1 + (jh >= 2)) : 0) * 3 +
                ((ww == 15) ? (1 + (jw >= 2)) : 0);
#pragma unroll
    for (int qt2 = 0; qt2 < 2; qt2++) {
      int qt = qh * 2 + qt2;
#pragma unroll
      for (int kt = 0; kt < 4; kt++) {
        const float* rb = &rp[(qt - kt + 3) * 49 + (lhi - jh + 3) * 7 + (3 - jw)];
#pragma unroll
        for (int e = 0; e < 4; e++) {
          float val = fmaf(s[qt2][kt][e], kScale, rb[e]);
          if (shifted) {
            int ci = ((wd == 7) ? (1 + (qt >= 2)) : 0) * 9 + mi_h * 3 +
                     ((ww == 15) ? (1 + (e >= 2)) : 0);
            int cj = ((wd == 7) ? (1 + (kt >= 2)) : 0) * 9 + mj_hw;
            if (ci != cj) val -= 100.f;
          }
          s[qt2][kt][e] = val;
        }
      }
    }
    // softmax per row (qt2, e): local max/sum over kt, butterfly over llo
#pragma unroll
    for (int qt2 = 0; qt2 < 2; qt2++) {
      f32x4 m;
#pragma unroll
      for (int e = 0; e < 4; e++)
        m[e] = fmaxf(fmaxf(s[qt2][0][e], s[qt2][1][e]), fmaxf(s[qt2][2][e], s[qt2][3][e]));
#pragma unroll
      for (int msk = 1; msk <= 8; msk <<= 1)
#pragma unroll
        for (int e = 0; e < 4; e++) m[e] = fmaxf(m[e], __shfl_xor(m[e], msk));
      f32x4 sum2 = (f32x4){0.f, 0.f, 0.f, 0.f};
#pragma unroll
      for (int kt = 0; kt < 4; kt++)
#pragma unroll
        for (int e = 0; e < 4; e++) {
          float p = __expf(s[qt2][kt][e] - m[e]);
          s[qt2][kt][e] = p;
          sum2[e] += p;
        }
#pragma unroll
      for (int msk = 1; msk <= 8; msk <<= 1)
#pragma unroll
        for (int e = 0; e < 4; e++) sum2[e] += __shfl_xor(sum2[e], msk);
#pragma unroll
      for (int e = 0; e < 4; e++) sum2[e] = 1.f / sum2[e];
#pragma unroll
      for (int kt = 0; kt < 4; kt++)
#pragma unroll
        for (int e = 0; e < 4; e++) s[qt2][kt][e] *= sum2[e];
    }
  }
  __syncthreads();  // all QK reads complete -> safe to overlay P
  if (active) {
#pragma unroll
    for (int qt2 = 0; qt2 < 2; qt2++)
#pragma unroll
      for (int kt = 0; kt < 4; kt++)
#pragma unroll
        for (int e = 0; e < 4; e++)
          plw[(qt2 * 16 + lhi * 4 + e) * 66 + kt * 16 + llo] = f2bf(s[qt2][kt][e]);
  }
  __syncthreads();
  if (active) {
    f32x4 o[2][2];
#pragma unroll
    for (int qt2 = 0; qt2 < 2; qt2++) {
      o[qt2][0] = (f32x4){0.f, 0.f, 0.f, 0.f};
      o[qt2][1] = (f32x4){0.f, 0.f, 0.f, 0.f};
#pragma unroll
      for (int ks = 0; ks < 2; ks++) {
        bf16x8 pa = *(const bf16x8*)&plw[(qt2 * 16 + llo) * 66 + ks * 32 + lhi * 8];
        o[qt2][0] = __builtin_amdgcn_mfma_f32_16x16x32_bf16(pa, bv[0][ks], o[qt2][0], 0, 0, 0);
        o[qt2][1] = __builtin_amdgcn_mfma_f32_16x16x32_bf16(pa, bv[1][ks], o[qt2][1], 0, 0, 0);
      }
    }
    u16* ob = out + (size_t)widx * 64 * 96 + head * 32;
#pragma unroll
    for (int qt2 = 0; qt2 < 2; qt2++)
#pragma unroll
      for (int jt = 0; jt < 2; jt++)
#pragma unroll
        for (int e = 0; e < 4; e++)
          ob[(size_t)(qh * 32 + qt2 * 16 + lhi * 4 + e) * 96 + jt * 16 + llo] =
              f2bf(o[qt2][jt][e]);
  }
}

// ---------------- proj GEMM + residual + LN2 (fused, zero LDS) --------------
// Block = 128 natural rows x 96 cols, 4 waves. A-frags gathered from global;
// B-frags direct from global bf16 W; residual prefetched; no barriers.
__global__ __launch_bounds__(256, 3) void k_proj(const u16* __restrict__ X,
                                                 const u16* __restrict__ Wp,
                                                 const float* __restrict__ bias,
                                                 u16* __restrict__ obf,
                                                 float* __restrict__ oadd,
                                                 const float* __restrict__ lng,
                                                 const float* __restrict__ lnb,
                                                 int shifted) {
  int tid = threadIdx.x;
  int wv = tid >> 6, lane = tid & 63;
  int llo = lane & 15, lhi = lane >> 4;
  int r0 = blockIdx.x << 7;

  // prefetch residual (natural row order)
  float resid[2][4][6];
#pragma unroll
  for (int i = 0; i < 2; i++)
#pragma unroll
    for (int rg = 0; rg < 4; rg++) {
      int row = r0 + wv * 32 + i * 16 + lhi * 4 + rg;
#pragma unroll
      for (int j = 0; j < 6; j++)
        resid[i][rg][j] = oadd[(size_t)row * 96 + j * 16 + llo];
    }

  // A-frag loads (window-gathered rows)
  bf16x8 a[2][3];
#pragma unroll
  for (int i = 0; i < 2; i++) {
    int r = r0 + wv * 32 + i * 16 + llo;
    int w = r & 63, h = (r >> 6) & 63, d = (r >> 12) & 31, bb = r >> 17;
    if (shifted) { d = (d + 30) & 31; h = (h + 62) & 63; w = (w + 62) & 63; }
    int widx = ((bb * 8 + (d >> 2)) * 16 + (h >> 2)) * 16 + (w >> 2);
    int rsrc = (widx << 6) + ((d & 3) << 4) + ((h & 3) << 2) + (w & 3);
#pragma unroll
    for (int ks = 0; ks < 3; ks++)
      a[i][ks] = *(const bf16x8*)(X + (size_t)rsrc * 96 + ks * 32 + lhi * 8);
  }

  f32x4 acc[2][6];
#pragma unroll
  for (int i = 0; i < 2; i++)
#pragma unroll
    for (int j = 0; j < 6; j++) acc[i][j] = (f32x4){0.f, 0.f, 0.f, 0.f};
#pragma unroll
  for (int ks = 0; ks < 3; ks++) {
    bf16x8 b[6];
#pragma unroll
    for (int j = 0; j < 6; j++)
      b[j] = *(const bf16x8*)(Wp + (size_t)(j * 16 + llo) * 96 + ks * 32 + lhi * 8);
#pragma unroll
    for (int i = 0; i < 2; i++)
#pragma unroll
      for (int j = 0; j < 6; j++)
        acc[i][j] = __builtin_amdgcn_mfma_f32_16x16x32_bf16(a[i][ks], b[j], acc[i][j], 0, 0, 0);
  }

  // epilogue: +bias +resid -> bx, then LN -> bf16 obf
  float bj[6], gj[6], betaj[6];
#pragma unroll
  for (int j = 0; j < 6; j++) {
    int col = j * 16 + llo;
    bj[j] = bias[col]; gj[j] = lng[col]; betaj[j] = lnb[col];
  }
#pragma unroll
  for (int i = 0; i < 2; i++) {
#pragma unroll
    for (int rg = 0; rg < 4; rg++) {
      int row = r0 + wv * 32 + i * 16 + lhi * 4 + rg;
      float vv[6], sum = 0.f;
#pragma unroll
      for (int j = 0; j < 6; j++) {
        vv[j] = acc[i][j][rg] + bj[j] + resid[i][rg][j];
        sum += vv[j];
      }
#pragma unroll
      for (int m = 1; m <= 8; m <<= 1) sum += __shfl_xor(sum, m);
      float mean = sum * (1.f / 96.f);
      float vs = 0.f;
#pragma unroll
      for (int j = 0; j < 6; j++) { float dd = vv[j] - mean; vs += dd * dd; }
#pragma unroll
      for (int m = 1; m <= 8; m <<= 1) vs += __shfl_xor(vs, m);
      float rstd = rsqrtf(vs * (1.f / 96.f) + 1e-5f);
#pragma unroll
      for (int j = 0; j < 6; j++) {
        int col = j * 16 + llo;
        oadd[(size_t)row * 96 + col] = vv[j];
        obf[(size_t)row * 96 + col] = f2bf((vv[j] - mean) * rstd * gj[j] + betaj[j]);
      }
    }
  }
}

// ---------------- fused MLP: fc1 + GELU + fc2 + residual (barrier-free) -----
// Block = 64 rows, 4 waves (each 16 rows x ALL cols). Hidden in LDS, chunked
// [4][64][104] (2-way max on b128 reads). Waves touch only their own rows ->
// NO __syncthreads anywhere. B-frags direct from global bf16 W.
__global__ __launch_bounds__(256, 3) void k_mlp(const u16* __restrict__ X,
                                                const u16* __restrict__ W1,
                                                const float* __restrict__ b1,
                                                const u16* __restrict__ W2,
                                                const float* __restrict__ b2,
                                                float* __restrict__ bx) {
  __shared__ __align__(16) u16 Hs[4 * 64 * 104];
  int tid = threadIdx.x, wv = tid >> 6, lane = tid & 63;
  int llo = lane & 15, lhi = lane >> 4;
  int r0 = blockIdx.x << 6;
  int rowb = wv * 16;

  // prefetch residual
  float resid[4][6];
#pragma unroll
  for (int rg = 0; rg < 4; rg++) {
    int row = r0 + rowb + lhi * 4 + rg;
#pragma unroll
    for (int j = 0; j < 6; j++)
      resid[rg][j] = bx[(size_t)row * 96 + j * 16 + llo];
  }

  // X A-frags (LN2 output)
  const u16* xr = X + (size_t)(r0 + rowb + llo) * 96;
  bf16x8 ax[3];
#pragma unroll
  for (int ks = 0; ks < 3; ks++) ax[ks] = *(const bf16x8*)(xr + ks * 32 + lhi * 8);

  // ---- fc1 + GELU -> Hs (no barriers) ----
  for (int c = 0; c < 4; c++) {
    f32x4 acc[6];
#pragma unroll
    for (int j = 0; j < 6; j++) acc[j] = (f32x4){0.f, 0.f, 0.f, 0.f};
#pragma unroll
    for (int ks = 0; ks < 3; ks++)
#pragma unroll
      for (int j = 0; j < 6; j++) {
        bf16x8 b = *(const bf16x8*)(W1 + (size_t)(c * 96 + j * 16 + llo) * 96 +
                                    ks * 32 + lhi * 8);
        acc[j] = __builtin_amdgcn_mfma_f32_16x16x32_bf16(ax[ks], b, acc[j], 0, 0, 0);
      }
#pragma unroll
    for (int j = 0; j < 6; j++) {
      float bb_ = b1[c * 96 + j * 16 + llo];
#pragma unroll
      for (int rg = 0; rg < 4; rg++) {
        float v = acc[j][rg] + bb_;
        Hs[(c * 64 + rowb + lhi * 4 + rg) * 104 + j * 16 + llo] =
            f2bf(0.5f * v * (1.f + erff(v * 0.70710678118654752f)));
      }
    }
  }

  // ---- fc2 (reads only this wave's own Hs rows -> no barrier) ----
  f32x4 acc2[6];
#pragma unroll
  for (int j = 0; j < 6; j++) acc2[j] = (f32x4){0.f, 0.f, 0.f, 0.f};
  for (int kc = 0; kc < 4; kc++) {
    bf16x8 ah[3];
#pragma unroll
    for (int ks = 0; ks < 3; ks++)
      ah[ks] = *(const bf16x8*)&Hs[(kc * 64 + rowb + llo) * 104 + ks * 32 + lhi * 8];
#pragma unroll
    for (int ks = 0; ks < 3; ks++)
#pragma unroll
      for (int j = 0; j < 6; j++) {
        bf16x8 b = *(const bf16x8*)(W2 + (size_t)(j * 16 + llo) * 384 + kc * 96 +
                                    ks * 32 + lhi * 8);
        acc2[j] = __builtin_amdgcn_mfma_f32_16x16x32_bf16(ah[ks], b, acc2[j], 0, 0, 0);
      }
  }

  // epilogue: + bias + residual -> bx
#pragma unroll
  for (int j = 0; j < 6; j++) {
    float bb_ = b2[j * 16 + llo];
#pragma unroll
    for (int rg = 0; rg < 4; rg++) {
      int row = r0 + rowb + lhi * 4 + rg;
      bx[(size_t)row * 96 + j * 16 + llo] = acc2[j][rg] + bb_ + resid[rg][j];
    }
  }
}

// ---------------- launcher ----------------
extern "C" void kernel_launch(void* const* d_in, const int* in_sizes, int n_in,
                              void* d_out, int out_size, void* d_ws, size_t ws_size,
                              hipStream_t stream) {
  const float* x_in = (const float*)d_in[0];
  const float* n1g = (const float*)d_in[1];
  const float* n1b = (const float*)d_in[2];
  const float* qkvw = (const float*)d_in[3];
  const float* qkvb = (const float*)d_in[4];
  const float* rpb = (const float*)d_in[5];
  const float* projw = (const float*)d_in[6];
  const float* projb = (const float*)d_in[7];
  const float* n2g = (const float*)d_in[8];
  const float* n2b = (const float*)d_in[9];
  const float* fc1w = (const float*)d_in[10];
  const float* fc1b = (const float*)d_in[11];
  const float* fc2w = (const float*)d_in[12];
  const float* fc2b = (const float*)d_in[13];
  float* outp = (float*)d_out;

  // workspace: bx fp32 (100.7 MB) | ba bf16 (50.3) | bb bf16 (50.3) | bf16 weights
  char* ws = (char*)d_ws;
  float* bx = (float*)ws;
  u16* ba = (u16*)(ws + 100663296);       // LN2 out (bf16)
  u16* bb = (u16*)(ws + 150994944);       // attn out (bf16)
  u16* wq_bf = (u16*)(ws + 201326592);    // 2 x 288 x 96
  u16* wp_bf = wq_bf + 2 * 288 * 96;      // 2 x 96 x 96
  u16* w1_bf = wp_bf + 2 * 96 * 96;       // 2 x 384 x 96
  u16* w2_bf = w1_bf + 2 * 384 * 96;      // 2 x 96 x 384

  k_tin<<<dim3(kS / 32, 3, kB), dim3(32, 8), 0, stream>>>(x_in, bx);
  k_wcvt<<<dim3(72, 4), 256, 0, stream>>>(qkvw, projw, fc1w, fc2w,
                                          wq_bf, wp_bf, w1_bf, w2_bf);

  for (int blk = 0; blk < 2; blk++) {
    int sh = blk;  // block 1 is shifted
    k_qa<<<kM / 128, 1024, 0, stream>>>(bx, n1g + blk * 96, n1b + blk * 96,
                                        wq_bf + blk * 288 * 96, qkvb + blk * 288,
                                        rpb + blk * 343 * 3, bb, sh);
    k_proj<<<kM / 128, 256, 0, stream>>>(bb, wp_bf + blk * 96 * 96, projb + blk * 96,
                                         ba, bx, n2g + blk * 96, n2b + blk * 96, sh);
    k_mlp<<<kM / 64, 256, 0, stream>>>(ba, w1_bf + blk * 384 * 96, fc1b + blk * 384,
                                       w2_bf + blk * 96 * 384, fc2b + blk * 96, bx);
  }

  k_tout<<<dim3(kS / 32, 3, kB), dim3(32, 8), 0, stream>>>(bx, outp);
}

// Round 10
// 862.751 us; speedup vs baseline: 1.1534x; 1.0621x over previous
//
#include <hip/hip_runtime.h>
#include <math.h>

typedef unsigned short u16;
typedef unsigned int u32;
#define DEVI __device__ __forceinline__

typedef __attribute__((ext_vector_type(8))) short bf16x8;
typedef __attribute__((ext_vector_type(4))) float f32x4;

// problem constants
constexpr int kB = 2, kC = 96, kD = 32, kH = 64, kW = 64;
constexpr int kS = kD * kH * kW;   // 131072 spatial positions per batch
constexpr int kM = kB * kS;        // 262144 total tokens
constexpr float kScale = 0.17677669529663687f;  // 32^-0.5

DEVI u16 f2bf(float f) {           // fp32 -> bf16 round-to-nearest-even
  u32 x = __float_as_uint(f);
  return (u16)((x + 0x7fffu + ((x >> 16) & 1u)) >> 16);
}
DEVI float bf2f(u16 v) { return __uint_as_float(((u32)v) << 16); }
DEVI u32 pack2(float a, float b) { return (u32)f2bf(a) | ((u32)f2bf(b) << 16); }

// exact-GELU via Abramowitz-Stegun 7.1.26 erf (|eps| <= 1.5e-7, << bf16 ulp)
DEVI float gelu_f(float v) {
  float x = v * 0.70710678118654752f;
  float ax = fabsf(x);
  float t = __builtin_amdgcn_rcpf(fmaf(0.3275911f, ax, 1.0f));
  float y = t * fmaf(t, fmaf(t, fmaf(t, fmaf(t, 1.061405429f, -1.453152027f),
                                     1.421413741f), -0.284496736f), 0.254829592f);
  float e = __expf(-x * x);
  float erfv = copysignf(fmaf(-y, e, 1.0f), x);
  return 0.5f * v * (1.0f + erfv);
}

// ---------------- transpose (B,C,S) <-> (B,S,C) ----------------
__global__ void k_tin(const float* __restrict__ in, float* __restrict__ out) {
  __shared__ float tile[32][33];
  int s0 = blockIdx.x << 5, c0 = blockIdx.y << 5, b = blockIdx.z;
  int tx = threadIdx.x, ty = threadIdx.y;
#pragma unroll
  for (int q = 0; q < 4; q++)
    tile[ty + q * 8][tx] = in[((size_t)(b * kC + c0 + ty + q * 8)) * kS + s0 + tx];
  __syncthreads();
#pragma unroll
  for (int q = 0; q < 4; q++)
    out[((size_t)(b * kS + s0 + ty + q * 8)) * kC + c0 + tx] = tile[tx][ty + q * 8];
}

__global__ void k_tout(const float* __restrict__ in, float* __restrict__ out) {
  __shared__ float tile[32][33];
  int s0 = blockIdx.x << 5, c0 = blockIdx.y << 5, b = blockIdx.z;
  int tx = threadIdx.x, ty = threadIdx.y;
#pragma unroll
  for (int q = 0; q < 4; q++)
    tile[ty + q * 8][tx] = in[((size_t)(b * kS + s0 + ty + q * 8)) * kC + c0 + tx];
  __syncthreads();
#pragma unroll
  for (int q = 0; q < 4; q++)
    out[((size_t)(b * kC + c0 + ty + q * 8)) * kS + s0 + tx] = tile[tx][ty + q * 8];
}

// ---------------- one-time weight fp32 -> bf16 conversion -------------------
__global__ __launch_bounds__(256) void k_wcvt(const float* __restrict__ q,
                                              const float* __restrict__ p,
                                              const float* __restrict__ f1,
                                              const float* __restrict__ f2,
                                              u16* dq, u16* dp, u16* df1, u16* df2) {
  int a = blockIdx.y;
  const float* sp; u16* dst; int n;
  if (a == 0)      { sp = q;  dst = dq;  n = 2 * 288 * 96; }
  else if (a == 1) { sp = p;  dst = dp;  n = 2 * 96 * 96; }
  else if (a == 2) { sp = f1; dst = df1; n = 2 * 384 * 96; }
  else             { sp = f2; dst = df2; n = 2 * 96 * 384; }
  for (int i = (blockIdx.x * 256 + threadIdx.x) * 4; i < n; i += gridDim.x * 1024) {
    float4 v = *(const float4*)(sp + i);
    *(u32*)(dst + i) = pack2(v.x, v.y);
    *(u32*)(dst + i + 2) = pack2(v.z, v.w);
  }
}

// ---------------- fused LN1 + QKV-GEMM + windowed attention (16 waves) ------
__global__ __launch_bounds__(1024, 4) void k_qa(const float* __restrict__ BX,
                                                const float* __restrict__ g1,
                                                const float* __restrict__ be1,
                                                const u16* __restrict__ Wq,
                                                const float* __restrict__ bq,
                                                const float* __restrict__ rpb,
                                                u16* __restrict__ out, int shifted) {
  __shared__ __align__(16) char arena[70720];
  u16* QK = (u16*)arena;                 // [128][200]: cols 0..95 Q, 96..191 K
  u16* VT = (u16*)(arena + 51200);       // [pair*3+head][32 d][40]: V^T
  float* RP = (float*)(arena + 66560);   // [3][343]

  int tid = threadIdx.x, wv = tid >> 6, lane = tid & 63;
  int llo = lane & 15, lhi = lane >> 4;
  int r0 = blockIdx.x << 7;
  int rowb = (wv >> 1) * 16;             // GEMM row base
  int colb = (wv & 1) * 48;              // GEMM col base

  for (int t = tid; t < 1029; t += 1024) {
    int head = t / 343, idx = t - head * 343;
    RP[t] = rpb[idx * 3 + head];
  }

  // ---- fused LN1: gather x row (window order -> natural), normalize ----
  {
    int r = r0 + rowb + llo;
    int wI = r >> 6, n = r & 63;
    int Xw = wI & 15, Xh = (wI >> 4) & 15, Xd = (wI >> 8) & 7, Xb = wI >> 11;
    int d = Xd * 4 + (n >> 4), h = Xh * 4 + ((n >> 2) & 3), w = Xw * 4 + (n & 3);
    if (shifted) { d = (d + 2) & 31; h = (h + 2) & 63; w = (w + 2) & 63; }
    const float* xr = BX + (size_t)(((Xb * kD + d) * kH + h) * kW + w) * 96;
    float xv[3][8];
#pragma unroll
    for (int ks = 0; ks < 3; ks++) {
      float4 p0 = *(const float4*)(xr + ks * 32 + lhi * 8);
      float4 p1 = *(const float4*)(xr + ks * 32 + lhi * 8 + 4);
      xv[ks][0] = p0.x; xv[ks][1] = p0.y; xv[ks][2] = p0.z; xv[ks][3] = p0.w;
      xv[ks][4] = p1.x; xv[ks][5] = p1.y; xv[ks][6] = p1.z; xv[ks][7] = p1.w;
    }
    float sum = 0.f;
#pragma unroll
    for (int ks = 0; ks < 3; ks++)
#pragma unroll
      for (int e = 0; e < 8; e++) sum += xv[ks][e];
    sum += __shfl_xor(sum, 16); sum += __shfl_xor(sum, 32);
    float mean = sum * (1.f / 96.f);
    float vs = 0.f;
#pragma unroll
    for (int ks = 0; ks < 3; ks++)
#pragma unroll
      for (int e = 0; e < 8; e++) { float dd = xv[ks][e] - mean; vs += dd * dd; }
    vs += __shfl_xor(vs, 16); vs += __shfl_xor(vs, 32);
    float rstd = rsqrtf(vs * (1.f / 96.f) + 1e-5f);
    bf16x8 a[3];
#pragma unroll
    for (int ks = 0; ks < 3; ks++) {
      const float* gp = g1 + ks * 32 + lhi * 8;
      const float* bp = be1 + ks * 32 + lhi * 8;
      float4 g0 = *(const float4*)gp, g4 = *(const float4*)(gp + 4);
      float4 b0 = *(const float4*)bp, b4 = *(const float4*)(bp + 4);
      float gf[8] = {g0.x, g0.y, g0.z, g0.w, g4.x, g4.y, g4.z, g4.w};
      float bf[8] = {b0.x, b0.y, b0.z, b0.w, b4.x, b4.y, b4.z, b4.w};
      bf16x8 t;
#pragma unroll
      for (int e = 0; e < 8; e++)
        t[e] = (short)f2bf((xv[ks][e] - mean) * rstd * gf[e] + bf[e]);
      a[ks] = t;
    }

    // ---- QKV GEMM: B-frags direct from global bf16 W, no barriers ----
    for (int c = 0; c < 3; c++) {
      f32x4 acc[3];
#pragma unroll
      for (int j = 0; j < 3; j++) acc[j] = (f32x4){0.f, 0.f, 0.f, 0.f};
#pragma unroll
      for (int ks = 0; ks < 3; ks++)
#pragma unroll
        for (int j = 0; j < 3; j++) {
          bf16x8 b = *(const bf16x8*)(Wq + (size_t)(c * 96 + colb + j * 16 + llo) * 96 +
                                      ks * 32 + lhi * 8);
          acc[j] = __builtin_amdgcn_mfma_f32_16x16x32_bf16(a[ks], b, acc[j], 0, 0, 0);
        }
      if (c < 2) {  // Q / K -> QK row-major
#pragma unroll
        for (int j = 0; j < 3; j++) {
          int col = colb + j * 16 + llo;
          float bb_ = bq[c * 96 + col];
#pragma unroll
          for (int rg = 0; rg < 4; rg++)
            QK[(rowb + lhi * 4 + rg) * 200 + c * 96 + col] = f2bf(acc[j][rg] + bb_);
        }
      } else {      // V -> VT transposed per (pair, head)
#pragma unroll
        for (int j = 0; j < 3; j++) {
          int dcol = colb + j * 16 + llo;
          float bb_ = bq[192 + dcol];
          int head = dcol >> 5, dd = dcol & 31;
#pragma unroll
          for (int rg = 0; rg < 4; rg++) {
            int row = rowb + lhi * 4 + rg;
            VT[(((row >> 6) * 3 + head) * 32 + dd) * 40 + (row & 63)] = f2bf(acc[j][rg] + bb_);
          }
        }
      }
    }
  }
  __syncthreads();

  // attention: 12 units = (pair, head, q-half); waves 12..15 idle
  int u = wv;
  bool active = (u < 12);
  int pair = u / 6, rem = u - pair * 6, head = rem >> 1, qh = rem & 1;
  int widx = (blockIdx.x << 1) + pair;
  int ww = widx & 15, wh = (widx >> 4) & 15, wd = (widx >> 8) & 7;
  const float* rp = RP + head * 343;
  const u16* qkw = QK + pair * 64 * 200;
  u16* plw = QK + u * 2112;              // P overlay on dead QK (32 x stride 66)

  f32x4 s[2][4];
  bf16x8 bv[2][2];
  if (active) {
    bf16x8 aq[2], bk[4];
#pragma unroll
    for (int qt2 = 0; qt2 < 2; qt2++)
      aq[qt2] = *(const bf16x8*)&qkw[(qh * 32 + qt2 * 16 + llo) * 200 + head * 32 + lhi * 8];
#pragma unroll
    for (int kt = 0; kt < 4; kt++)
      bk[kt] = *(const bf16x8*)&qkw[(kt * 16 + llo) * 200 + 96 + head * 32 + lhi * 8];
    const u16* vtb = VT + (pair * 3 + head) * 32 * 40;
#pragma unroll
    for (int jt = 0; jt < 2; jt++)
#pragma unroll
      for (int ks = 0; ks < 2; ks++)
        bv[jt][ks] = *(const bf16x8*)&vtb[(jt * 16 + llo) * 40 + ks * 32 + lhi * 8];

#pragma unroll
    for (int qt2 = 0; qt2 < 2; qt2++)
#pragma unroll
      for (int kt = 0; kt < 4; kt++)
        s[qt2][kt] = __builtin_amdgcn_mfma_f32_16x16x32_bf16(
            aq[qt2], bk[kt], (f32x4){0.f, 0.f, 0.f, 0.f}, 0, 0, 0);

    int jh = llo >> 2, jw = llo & 3;
    int mi_h = (wh == 15) ? (1 + (lhi >= 2)) : 0;
    int mj_hw = ((wh == 15) ? (1 + (jh >= 2)) : 0) * 3 +
                ((ww == 15) ? (1 + (jw >= 2)) : 0);
#pragma unroll
    for (int qt2 = 0; qt2 < 2; qt2++) {
      int qt = qh * 2 + qt2;
#pragma unroll
      for (int kt = 0; kt < 4; kt++) {
        const float* rb = &rp[(qt - kt + 3) * 49 + (lhi - jh + 3) * 7 + (3 - jw)];
#pragma unroll
        for (int e = 0; e < 4; e++) {
          float val = fmaf(s[qt2][kt][e], kScale, rb[e]);
          if (shifted) {
            int ci = ((wd == 7) ? (1 + (qt >= 2)) : 0) * 9 + mi_h * 3 +
                     ((ww == 15) ? (1 + (e >= 2)) : 0);
            int cj = ((wd == 7) ? (1 + (kt >= 2)) : 0) * 9 + mj_hw;
            if (ci != cj) val -= 100.f;
          }
          s[qt2][kt][e] = val;
        }
      }
    }
    // softmax per row (qt2, e): local max/sum over kt, butterfly over llo
#pragma unroll
    for (int qt2 = 0; qt2 < 2; qt2++) {
      f32x4 m;
#pragma unroll
      for (int e = 0; e < 4; e++)
        m[e] = fmaxf(fmaxf(s[qt2][0][e], s[qt2][1][e]), fmaxf(s[qt2][2][e], s[qt2][3][e]));
#pragma unroll
      for (int msk = 1; msk <= 8; msk <<= 1)
#pragma unroll
        for (int e = 0; e < 4; e++) m[e] = fmaxf(m[e], __shfl_xor(m[e], msk));
      f32x4 sum2 = (f32x4){0.f, 0.f, 0.f, 0.f};
#pragma unroll
      for (int kt = 0; kt < 4; kt++)
#pragma unroll
        for (int e = 0; e < 4; e++) {
          float p = __expf(s[qt2][kt][e] - m[e]);
          s[qt2][kt][e] = p;
          sum2[e] += p;
        }
#pragma unroll
      for (int msk = 1; msk <= 8; msk <<= 1)
#pragma unroll
        for (int e = 0; e < 4; e++) sum2[e] += __shfl_xor(sum2[e], msk);
#pragma unroll
      for (int e = 0; e < 4; e++) sum2[e] = 1.f / sum2[e];
#pragma unroll
      for (int kt = 0; kt < 4; kt++)
#pragma unroll
        for (int e = 0; e < 4; e++) s[qt2][kt][e] *= sum2[e];
    }
  }
  __syncthreads();  // all QK reads complete -> safe to overlay P
  if (active) {
#pragma unroll
    for (int qt2 = 0; qt2 < 2; qt2++)
#pragma unroll
      for (int kt = 0; kt < 4; kt++)
#pragma unroll
        for (int e = 0; e < 4; e++)
          plw[(qt2 * 16 + lhi * 4 + e) * 66 + kt * 16 + llo] = f2bf(s[qt2][kt][e]);
  }
  __syncthreads();
  if (active) {
    f32x4 o[2][2];
#pragma unroll
    for (int qt2 = 0; qt2 < 2; qt2++) {
      o[qt2][0] = (f32x4){0.f, 0.f, 0.f, 0.f};
      o[qt2][1] = (f32x4){0.f, 0.f, 0.f, 0.f};
#pragma unroll
      for (int ks = 0; ks < 2; ks++) {
        bf16x8 pa = *(const bf16x8*)&plw[(qt2 * 16 + llo) * 66 + ks * 32 + lhi * 8];
        o[qt2][0] = __builtin_amdgcn_mfma_f32_16x16x32_bf16(pa, bv[0][ks], o[qt2][0], 0, 0, 0);
        o[qt2][1] = __builtin_amdgcn_mfma_f32_16x16x32_bf16(pa, bv[1][ks], o[qt2][1], 0, 0, 0);
      }
    }
    u16* ob = out + (size_t)widx * 64 * 96 + head * 32;
#pragma unroll
    for (int qt2 = 0; qt2 < 2; qt2++)
#pragma unroll
      for (int jt = 0; jt < 2; jt++)
#pragma unroll
        for (int e = 0; e < 4; e++)
          ob[(size_t)(qh * 32 + qt2 * 16 + lhi * 4 + e) * 96 + jt * 16 + llo] =
              f2bf(o[qt2][jt][e]);
  }
}

// ---------------- proj GEMM + residual + LN2 (fused, zero LDS) --------------
__global__ __launch_bounds__(256, 3) void k_proj(const u16* __restrict__ X,
                                                 const u16* __restrict__ Wp,
                                                 const float* __restrict__ bias,
                                                 u16* __restrict__ obf,
                                                 float* __restrict__ oadd,
                                                 const float* __restrict__ lng,
                                                 const float* __restrict__ lnb,
                                                 int shifted) {
  int tid = threadIdx.x;
  int wv = tid >> 6, lane = tid & 63;
  int llo = lane & 15, lhi = lane >> 4;
  int r0 = blockIdx.x << 7;

  // prefetch residual (natural row order)
  float resid[2][4][6];
#pragma unroll
  for (int i = 0; i < 2; i++)
#pragma unroll
    for (int rg = 0; rg < 4; rg++) {
      int row = r0 + wv * 32 + i * 16 + lhi * 4 + rg;
#pragma unroll
      for (int j = 0; j < 6; j++)
        resid[i][rg][j] = oadd[(size_t)row * 96 + j * 16 + llo];
    }

  // A-frag loads (window-gathered rows)
  bf16x8 a[2][3];
#pragma unroll
  for (int i = 0; i < 2; i++) {
    int r = r0 + wv * 32 + i * 16 + llo;
    int w = r & 63, h = (r >> 6) & 63, d = (r >> 12) & 31, bb = r >> 17;
    if (shifted) { d = (d + 30) & 31; h = (h + 62) & 63; w = (w + 62) & 63; }
    int widx = ((bb * 8 + (d >> 2)) * 16 + (h >> 2)) * 16 + (w >> 2);
    int rsrc = (widx << 6) + ((d & 3) << 4) + ((h & 3) << 2) + (w & 3);
#pragma unroll
    for (int ks = 0; ks < 3; ks++)
      a[i][ks] = *(const bf16x8*)(X + (size_t)rsrc * 96 + ks * 32 + lhi * 8);
  }

  f32x4 acc[2][6];
#pragma unroll
  for (int i = 0; i < 2; i++)
#pragma unroll
    for (int j = 0; j < 6; j++) acc[i][j] = (f32x4){0.f, 0.f, 0.f, 0.f};
#pragma unroll
  for (int ks = 0; ks < 3; ks++) {
    bf16x8 b[6];
#pragma unroll
    for (int j = 0; j < 6; j++)
      b[j] = *(const bf16x8*)(Wp + (size_t)(j * 16 + llo) * 96 + ks * 32 + lhi * 8);
#pragma unroll
    for (int i = 0; i < 2; i++)
#pragma unroll
      for (int j = 0; j < 6; j++)
        acc[i][j] = __builtin_amdgcn_mfma_f32_16x16x32_bf16(a[i][ks], b[j], acc[i][j], 0, 0, 0);
  }

  // epilogue: +bias +resid -> bx, then LN -> bf16 obf
  float bj[6], gj[6], betaj[6];
#pragma unroll
  for (int j = 0; j < 6; j++) {
    int col = j * 16 + llo;
    bj[j] = bias[col]; gj[j] = lng[col]; betaj[j] = lnb[col];
  }
#pragma unroll
  for (int i = 0; i < 2; i++) {
#pragma unroll
    for (int rg = 0; rg < 4; rg++) {
      int row = r0 + wv * 32 + i * 16 + lhi * 4 + rg;
      float vv[6], sum = 0.f;
#pragma unroll
      for (int j = 0; j < 6; j++) {
        vv[j] = acc[i][j][rg] + bj[j] + resid[i][rg][j];
        sum += vv[j];
      }
#pragma unroll
      for (int m = 1; m <= 8; m <<= 1) sum += __shfl_xor(sum, m);
      float mean = sum * (1.f / 96.f);
      float vs = 0.f;
#pragma unroll
      for (int j = 0; j < 6; j++) { float dd = vv[j] - mean; vs += dd * dd; }
#pragma unroll
      for (int m = 1; m <= 8; m <<= 1) vs += __shfl_xor(vs, m);
      float rstd = rsqrtf(vs * (1.f / 96.f) + 1e-5f);
#pragma unroll
      for (int j = 0; j < 6; j++) {
        int col = j * 16 + llo;
        oadd[(size_t)row * 96 + col] = vv[j];
        obf[(size_t)row * 96 + col] = f2bf((vv[j] - mean) * rstd * gj[j] + betaj[j]);
      }
    }
  }
}

// ---------------- fused MLP v3: chunk-interleaved fc1+GELU+fc2 --------------
// Block = 128 rows, 4 waves (each 32 rows = 2 A-frag groups). Per 96-col
// hidden chunk: fc1 MFMA -> GELU -> Hs (wave-private rows, no barrier) ->
// fc2 partial accumulate. Hidden never materializes beyond one chunk;
// fc1/fc2 load+MFMA chains interleave for 2x memory-level parallelism.
__global__ __launch_bounds__(256) void k_mlp(const u16* __restrict__ X,
                                             const u16* __restrict__ W1,
                                             const float* __restrict__ b1,
                                             const u16* __restrict__ W2,
                                             const float* __restrict__ b2,
                                             float* __restrict__ bx) {
  __shared__ __align__(16) u16 Hs[128 * 104];
  int tid = threadIdx.x, wv = tid >> 6, lane = tid & 63;
  int llo = lane & 15, lhi = lane >> 4;
  int r0 = blockIdx.x << 7;
  int rowb = wv * 32;

  // X A-frags for 2 row groups (reused by all 4 fc1 chunks)
  bf16x8 ax[2][3];
#pragma unroll
  for (int i = 0; i < 2; i++) {
    const u16* xr = X + (size_t)(r0 + rowb + i * 16 + llo) * 96;
#pragma unroll
    for (int ks = 0; ks < 3; ks++) ax[i][ks] = *(const bf16x8*)(xr + ks * 32 + lhi * 8);
  }

  f32x4 acc2[2][6];
#pragma unroll
  for (int i = 0; i < 2; i++)
#pragma unroll
    for (int j = 0; j < 6; j++) acc2[i][j] = (f32x4){0.f, 0.f, 0.f, 0.f};

  for (int c = 0; c < 4; c++) {
    // fc1 chunk: 96 hidden cols
    f32x4 acc[2][6];
#pragma unroll
    for (int i = 0; i < 2; i++)
#pragma unroll
      for (int j = 0; j < 6; j++) acc[i][j] = (f32x4){0.f, 0.f, 0.f, 0.f};
#pragma unroll
    for (int ks = 0; ks < 3; ks++)
#pragma unroll
      for (int j = 0; j < 6; j++) {
        bf16x8 b = *(const bf16x8*)(W1 + (size_t)(c * 96 + j * 16 + llo) * 96 +
                                    ks * 32 + lhi * 8);
        acc[0][j] = __builtin_amdgcn_mfma_f32_16x16x32_bf16(ax[0][ks], b, acc[0][j], 0, 0, 0);
        acc[1][j] = __builtin_amdgcn_mfma_f32_16x16x32_bf16(ax[1][ks], b, acc[1][j], 0, 0, 0);
      }
    // GELU -> Hs (wave-private rows; same-wave LDS ordering, no barrier)
#pragma unroll
    for (int j = 0; j < 6; j++) {
      float bb_ = b1[c * 96 + j * 16 + llo];
#pragma unroll
      for (int i = 0; i < 2; i++)
#pragma unroll
        for (int rg = 0; rg < 4; rg++)
          Hs[(rowb + i * 16 + lhi * 4 + rg) * 104 + j * 16 + llo] =
              f2bf(gelu_f(acc[i][j][rg] + bb_));
    }
    // fc2 partial accumulate from this chunk
    bf16x8 ah[2][3];
#pragma unroll
    for (int i = 0; i < 2; i++)
#pragma unroll
      for (int ks = 0; ks < 3; ks++)
        ah[i][ks] = *(const bf16x8*)&Hs[(rowb + i * 16 + llo) * 104 + ks * 32 + lhi * 8];
#pragma unroll
    for (int ks = 0; ks < 3; ks++)
#pragma unroll
      for (int j = 0; j < 6; j++) {
        bf16x8 b = *(const bf16x8*)(W2 + (size_t)(j * 16 + llo) * 384 + c * 96 +
                                    ks * 32 + lhi * 8);
        acc2[0][j] = __builtin_amdgcn_mfma_f32_16x16x32_bf16(ah[0][ks], b, acc2[0][j], 0, 0, 0);
        acc2[1][j] = __builtin_amdgcn_mfma_f32_16x16x32_bf16(ah[1][ks], b, acc2[1][j], 0, 0, 0);
      }
  }

  // epilogue: + bias + residual -> bx
#pragma unroll
  for (int i = 0; i < 2; i++)
#pragma unroll
    for (int j = 0; j < 6; j++) {
      float bb_ = b2[j * 16 + llo];
#pragma unroll
      for (int rg = 0; rg < 4; rg++) {
        size_t off = (size_t)(r0 + rowb + i * 16 + lhi * 4 + rg) * 96 + j * 16 + llo;
        bx[off] += acc2[i][j][rg] + bb_;
      }
    }
}

// ---------------- launcher ----------------
extern "C" void kernel_launch(void* const* d_in, const int* in_sizes, int n_in,
                              void* d_out, int out_size, void* d_ws, size_t ws_size,
                              hipStream_t stream) {
  const float* x_in = (const float*)d_in[0];
  const float* n1g = (const float*)d_in[1];
  const float* n1b = (const float*)d_in[2];
  const float* qkvw = (const float*)d_in[3];
  const float* qkvb = (const float*)d_in[4];
  const float* rpb = (const float*)d_in[5];
  const float* projw = (const float*)d_in[6];
  const float* projb = (const float*)d_in[7];
  const float* n2g = (const float*)d_in[8];
  const float* n2b = (const float*)d_in[9];
  const float* fc1w = (const float*)d_in[10];
  const float* fc1b = (const float*)d_in[11];
  const float* fc2w = (const float*)d_in[12];
  const float* fc2b = (const float*)d_in[13];
  float* outp = (float*)d_out;

  // workspace: bx fp32 (100.7 MB) | ba bf16 (50.3) | bb bf16 (50.3) | bf16 weights
  char* ws = (char*)d_ws;
  float* bx = (float*)ws;
  u16* ba = (u16*)(ws + 100663296);       // LN2 out (bf16)
  u16* bb = (u16*)(ws + 150994944);       // attn out (bf16)
  u16* wq_bf = (u16*)(ws + 201326592);    // 2 x 288 x 96
  u16* wp_bf = wq_bf + 2 * 288 * 96;      // 2 x 96 x 96
  u16* w1_bf = wp_bf + 2 * 96 * 96;       // 2 x 384 x 96
  u16* w2_bf = w1_bf + 2 * 384 * 96;      // 2 x 96 x 384

  k_tin<<<dim3(kS / 32, 3, kB), dim3(32, 8), 0, stream>>>(x_in, bx);
  k_wcvt<<<dim3(72, 4), 256, 0, stream>>>(qkvw, projw, fc1w, fc2w,
                                          wq_bf, wp_bf, w1_bf, w2_bf);

  for (int blk = 0; blk < 2; blk++) {
    int sh = blk;  // block 1 is shifted
    k_qa<<<kM / 128, 1024, 0, stream>>>(bx, n1g + blk * 96, n1b + blk * 96,
                                        wq_bf + blk * 288 * 96, qkvb + blk * 288,
                                        rpb + blk * 343 * 3, bb, sh);
    k_proj<<<kM / 128, 256, 0, stream>>>(bb, wp_bf + blk * 96 * 96, projb + blk * 96,
                                         ba, bx, n2g + blk * 96, n2b + blk * 96, sh);
    k_mlp<<<kM / 128, 256, 0, stream>>>(ba, w1_bf + blk * 384 * 96, fc1b + blk * 384,
                                        w2_bf + blk * 96 * 384, fc2b + blk * 96, bx);
  }

  k_tout<<<dim3(kS / 32, 3, kB), dim3(32, 8), 0, stream>>>(bx, outp);
}

// Round 11
// 728.035 us; speedup vs baseline: 1.3668x; 1.1850x over previous
//
#include <hip/hip_runtime.h>
#include <math.h>

typedef unsigned short u16;
typedef unsigned int u32;
#define DEVI __device__ __forceinline__

typedef __attribute__((ext_vector_type(8))) short bf16x8;
typedef __attribute__((ext_vector_type(4))) float f32x4;

// problem constants
constexpr int kB = 2, kC = 96, kD = 32, kH = 64, kW = 64;
constexpr int kS = kD * kH * kW;   // 131072 spatial positions per batch
constexpr int kM = kB * kS;        // 262144 total tokens
constexpr float kScale = 0.17677669529663687f;  // 32^-0.5

DEVI u16 f2bf(float f) {           // fp32 -> bf16 round-to-nearest-even
  u32 x = __float_as_uint(f);
  return (u16)((x + 0x7fffu + ((x >> 16) & 1u)) >> 16);
}
DEVI float bf2f(u16 v) { return __uint_as_float(((u32)v) << 16); }
DEVI u32 pack2(float a, float b) { return (u32)f2bf(a) | ((u32)f2bf(b) << 16); }

// exact-GELU via Abramowitz-Stegun 7.1.26 erf (|eps| <= 1.5e-7, << bf16 ulp)
DEVI float gelu_f(float v) {
  float x = v * 0.70710678118654752f;
  float ax = fabsf(x);
  float t = __builtin_amdgcn_rcpf(fmaf(0.3275911f, ax, 1.0f));
  float y = t * fmaf(t, fmaf(t, fmaf(t, fmaf(t, 1.061405429f, -1.453152027f),
                                     1.421413741f), -0.284496736f), 0.254829592f);
  float e = __expf(-x * x);
  float erfv = copysignf(fmaf(-y, e, 1.0f), x);
  return 0.5f * v * (1.0f + erfv);
}

// ---------------- transpose (B,C,S) <-> (B,S,C) ----------------
__global__ void k_tin(const float* __restrict__ in, float* __restrict__ out) {
  __shared__ float tile[32][33];
  int s0 = blockIdx.x << 5, c0 = blockIdx.y << 5, b = blockIdx.z;
  int tx = threadIdx.x, ty = threadIdx.y;
#pragma unroll
  for (int q = 0; q < 4; q++)
    tile[ty + q * 8][tx] = in[((size_t)(b * kC + c0 + ty + q * 8)) * kS + s0 + tx];
  __syncthreads();
#pragma unroll
  for (int q = 0; q < 4; q++)
    out[((size_t)(b * kS + s0 + ty + q * 8)) * kC + c0 + tx] = tile[tx][ty + q * 8];
}

__global__ void k_tout(const float* __restrict__ in, float* __restrict__ out) {
  __shared__ float tile[32][33];
  int s0 = blockIdx.x << 5, c0 = blockIdx.y << 5, b = blockIdx.z;
  int tx = threadIdx.x, ty = threadIdx.y;
#pragma unroll
  for (int q = 0; q < 4; q++)
    tile[ty + q * 8][tx] = in[((size_t)(b * kS + s0 + ty + q * 8)) * kC + c0 + tx];
  __syncthreads();
#pragma unroll
  for (int q = 0; q < 4; q++)
    out[((size_t)(b * kC + c0 + ty + q * 8)) * kS + s0 + tx] = tile[tx][ty + q * 8];
}

// ---------------- one-time weight fp32 -> bf16 conversion -------------------
__global__ __launch_bounds__(256) void k_wcvt(const float* __restrict__ q,
                                              const float* __restrict__ p,
                                              const float* __restrict__ f1,
                                              const float* __restrict__ f2,
                                              u16* dq, u16* dp, u16* df1, u16* df2) {
  int a = blockIdx.y;
  const float* sp; u16* dst; int n;
  if (a == 0)      { sp = q;  dst = dq;  n = 2 * 288 * 96; }
  else if (a == 1) { sp = p;  dst = dp;  n = 2 * 96 * 96; }
  else if (a == 2) { sp = f1; dst = df1; n = 2 * 384 * 96; }
  else             { sp = f2; dst = df2; n = 2 * 96 * 384; }
  for (int i = (blockIdx.x * 256 + threadIdx.x) * 4; i < n; i += gridDim.x * 1024) {
    float4 v = *(const float4*)(sp + i);
    *(u32*)(dst + i) = pack2(v.x, v.y);
    *(u32*)(dst + i + 2) = pack2(v.z, v.w);
  }
}

// ---------------- fused LN1 + QKV-GEMM + windowed attention (16 waves) ------
__global__ __launch_bounds__(1024, 4) void k_qa(const float* __restrict__ BX,
                                                const float* __restrict__ g1,
                                                const float* __restrict__ be1,
                                                const u16* __restrict__ Wq,
                                                const float* __restrict__ bq,
                                                const float* __restrict__ rpb,
                                                u16* __restrict__ out, int shifted) {
  __shared__ __align__(16) char arena[70720];
  u16* QK = (u16*)arena;                 // [128][200]: cols 0..95 Q, 96..191 K
  u16* VT = (u16*)(arena + 51200);       // [pair*3+head][32 d][40]: V^T
  float* RP = (float*)(arena + 66560);   // [3][343]

  int tid = threadIdx.x, wv = tid >> 6, lane = tid & 63;
  int llo = lane & 15, lhi = lane >> 4;
  int r0 = blockIdx.x << 7;
  int rowb = (wv >> 1) * 16;             // GEMM row base
  int colb = (wv & 1) * 48;              // GEMM col base

  for (int t = tid; t < 1029; t += 1024) {
    int head = t / 343, idx = t - head * 343;
    RP[t] = rpb[idx * 3 + head];
  }

  // ---- fused LN1: gather x row (window order -> natural), normalize ----
  {
    int r = r0 + rowb + llo;
    int wI = r >> 6, n = r & 63;
    int Xw = wI & 15, Xh = (wI >> 4) & 15, Xd = (wI >> 8) & 7, Xb = wI >> 11;
    int d = Xd * 4 + (n >> 4), h = Xh * 4 + ((n >> 2) & 3), w = Xw * 4 + (n & 3);
    if (shifted) { d = (d + 2) & 31; h = (h + 2) & 63; w = (w + 2) & 63; }
    const float* xr = BX + (size_t)(((Xb * kD + d) * kH + h) * kW + w) * 96;
    float xv[3][8];
#pragma unroll
    for (int ks = 0; ks < 3; ks++) {
      float4 p0 = *(const float4*)(xr + ks * 32 + lhi * 8);
      float4 p1 = *(const float4*)(xr + ks * 32 + lhi * 8 + 4);
      xv[ks][0] = p0.x; xv[ks][1] = p0.y; xv[ks][2] = p0.z; xv[ks][3] = p0.w;
      xv[ks][4] = p1.x; xv[ks][5] = p1.y; xv[ks][6] = p1.z; xv[ks][7] = p1.w;
    }
    float sum = 0.f;
#pragma unroll
    for (int ks = 0; ks < 3; ks++)
#pragma unroll
      for (int e = 0; e < 8; e++) sum += xv[ks][e];
    sum += __shfl_xor(sum, 16); sum += __shfl_xor(sum, 32);
    float mean = sum * (1.f / 96.f);
    float vs = 0.f;
#pragma unroll
    for (int ks = 0; ks < 3; ks++)
#pragma unroll
      for (int e = 0; e < 8; e++) { float dd = xv[ks][e] - mean; vs += dd * dd; }
    vs += __shfl_xor(vs, 16); vs += __shfl_xor(vs, 32);
    float rstd = rsqrtf(vs * (1.f / 96.f) + 1e-5f);
    bf16x8 a[3];
#pragma unroll
    for (int ks = 0; ks < 3; ks++) {
      const float* gp = g1 + ks * 32 + lhi * 8;
      const float* bp = be1 + ks * 32 + lhi * 8;
      float4 g0 = *(const float4*)gp, g4 = *(const float4*)(gp + 4);
      float4 b0 = *(const float4*)bp, b4 = *(const float4*)(bp + 4);
      float gf[8] = {g0.x, g0.y, g0.z, g0.w, g4.x, g4.y, g4.z, g4.w};
      float bf[8] = {b0.x, b0.y, b0.z, b0.w, b4.x, b4.y, b4.z, b4.w};
      bf16x8 t;
#pragma unroll
      for (int e = 0; e < 8; e++)
        t[e] = (short)f2bf((xv[ks][e] - mean) * rstd * gf[e] + bf[e]);
      a[ks] = t;
    }

    // ---- QKV GEMM: B-frags direct from global bf16 W, no barriers ----
    for (int c = 0; c < 3; c++) {
      f32x4 acc[3];
#pragma unroll
      for (int j = 0; j < 3; j++) acc[j] = (f32x4){0.f, 0.f, 0.f, 0.f};
#pragma unroll
      for (int ks = 0; ks < 3; ks++)
#pragma unroll
        for (int j = 0; j < 3; j++) {
          bf16x8 b = *(const bf16x8*)(Wq + (size_t)(c * 96 + colb + j * 16 + llo) * 96 +
                                      ks * 32 + lhi * 8);
          acc[j] = __builtin_amdgcn_mfma_f32_16x16x32_bf16(a[ks], b, acc[j], 0, 0, 0);
        }
      if (c < 2) {  // Q / K -> QK row-major
#pragma unroll
        for (int j = 0; j < 3; j++) {
          int col = colb + j * 16 + llo;
          float bb_ = bq[c * 96 + col];
#pragma unroll
          for (int rg = 0; rg < 4; rg++)
            QK[(rowb + lhi * 4 + rg) * 200 + c * 96 + col] = f2bf(acc[j][rg] + bb_);
        }
      } else {      // V -> VT transposed per (pair, head)
#pragma unroll
        for (int j = 0; j < 3; j++) {
          int dcol = colb + j * 16 + llo;
          float bb_ = bq[192 + dcol];
          int head = dcol >> 5, dd = dcol & 31;
#pragma unroll
          for (int rg = 0; rg < 4; rg++) {
            int row = rowb + lhi * 4 + rg;
            VT[(((row >> 6) * 3 + head) * 32 + dd) * 40 + (row & 63)] = f2bf(acc[j][rg] + bb_);
          }
        }
      }
    }
  }
  __syncthreads();

  // attention: 12 units = (pair, head, q-half); waves 12..15 idle
  int u = wv;
  bool active = (u < 12);
  int pair = u / 6, rem = u - pair * 6, head = rem >> 1, qh = rem & 1;
  int widx = (blockIdx.x << 1) + pair;
  int ww = widx & 15, wh = (widx >> 4) & 15, wd = (widx >> 8) & 7;
  const float* rp = RP + head * 343;
  const u16* qkw = QK + pair * 64 * 200;
  u16* plw = QK + u * 2112;              // P overlay on dead QK (32 x stride 66)

  f32x4 s[2][4];
  bf16x8 bv[2][2];
  if (active) {
    bf16x8 aq[2], bk[4];
#pragma unroll
    for (int qt2 = 0; qt2 < 2; qt2++)
      aq[qt2] = *(const bf16x8*)&qkw[(qh * 32 + qt2 * 16 + llo) * 200 + head * 32 + lhi * 8];
#pragma unroll
    for (int kt = 0; kt < 4; kt++)
      bk[kt] = *(const bf16x8*)&qkw[(kt * 16 + llo) * 200 + 96 + head * 32 + lhi * 8];
    const u16* vtb = VT + (pair * 3 + head) * 32 * 40;
#pragma unroll
    for (int jt = 0; jt < 2; jt++)
#pragma unroll
      for (int ks = 0; ks < 2; ks++)
        bv[jt][ks] = *(const bf16x8*)&vtb[(jt * 16 + llo) * 40 + ks * 32 + lhi * 8];

#pragma unroll
    for (int qt2 = 0; qt2 < 2; qt2++)
#pragma unroll
      for (int kt = 0; kt < 4; kt++)
        s[qt2][kt] = __builtin_amdgcn_mfma_f32_16x16x32_bf16(
            aq[qt2], bk[kt], (f32x4){0.f, 0.f, 0.f, 0.f}, 0, 0, 0);

    int jh = llo >> 2, jw = llo & 3;
    int mi_h = (wh == 15) ? (1 + (lhi >= 2)) : 0;
    int mj_hw = ((wh == 15) ? (1 + (jh >= 2)) : 0) * 3 +
                ((ww == 15) ? (1 + (jw >= 2)) : 0);
#pragma unroll
    for (int qt2 = 0; qt2 < 2; qt2++) {
      int qt = qh * 2 + qt2;
#pragma unroll
      for (int kt = 0; kt < 4; kt++) {
        const float* rb = &rp[(qt - kt + 3) * 49 + (lhi - jh + 3) * 7 + (3 - jw)];
#pragma unroll
        for (int e = 0; e < 4; e++) {
          float val = fmaf(s[qt2][kt][e], kScale, rb[e]);
          if (shifted) {
            int ci = ((wd == 7) ? (1 + (qt >= 2)) : 0) * 9 + mi_h * 3 +
                     ((ww == 15) ? (1 + (e >= 2)) : 0);
            int cj = ((wd == 7) ? (1 + (kt >= 2)) : 0) * 9 + mj_hw;
            if (ci != cj) val -= 100.f;
          }
          s[qt2][kt][e] = val;
        }
      }
    }
    // softmax per row (qt2, e): local max/sum over kt, butterfly over llo
#pragma unroll
    for (int qt2 = 0; qt2 < 2; qt2++) {
      f32x4 m;
#pragma unroll
      for (int e = 0; e < 4; e++)
        m[e] = fmaxf(fmaxf(s[qt2][0][e], s[qt2][1][e]), fmaxf(s[qt2][2][e], s[qt2][3][e]));
#pragma unroll
      for (int msk = 1; msk <= 8; msk <<= 1)
#pragma unroll
        for (int e = 0; e < 4; e++) m[e] = fmaxf(m[e], __shfl_xor(m[e], msk));
      f32x4 sum2 = (f32x4){0.f, 0.f, 0.f, 0.f};
#pragma unroll
      for (int kt = 0; kt < 4; kt++)
#pragma unroll
        for (int e = 0; e < 4; e++) {
          float p = __expf(s[qt2][kt][e] - m[e]);
          s[qt2][kt][e] = p;
          sum2[e] += p;
        }
#pragma unroll
      for (int msk = 1; msk <= 8; msk <<= 1)
#pragma unroll
        for (int e = 0; e < 4; e++) sum2[e] += __shfl_xor(sum2[e], msk);
#pragma unroll
      for (int e = 0; e < 4; e++) sum2[e] = 1.f / sum2[e];
#pragma unroll
      for (int kt = 0; kt < 4; kt++)
#pragma unroll
        for (int e = 0; e < 4; e++) s[qt2][kt][e] *= sum2[e];
    }
  }
  __syncthreads();  // all QK reads complete -> safe to overlay P
  if (active) {
#pragma unroll
    for (int qt2 = 0; qt2 < 2; qt2++)
#pragma unroll
      for (int kt = 0; kt < 4; kt++)
#pragma unroll
        for (int e = 0; e < 4; e++)
          plw[(qt2 * 16 + lhi * 4 + e) * 66 + kt * 16 + llo] = f2bf(s[qt2][kt][e]);
  }
  __syncthreads();
  if (active) {
    f32x4 o[2][2];
#pragma unroll
    for (int qt2 = 0; qt2 < 2; qt2++) {
      o[qt2][0] = (f32x4){0.f, 0.f, 0.f, 0.f};
      o[qt2][1] = (f32x4){0.f, 0.f, 0.f, 0.f};
#pragma unroll
      for (int ks = 0; ks < 2; ks++) {
        bf16x8 pa = *(const bf16x8*)&plw[(qt2 * 16 + llo) * 66 + ks * 32 + lhi * 8];
        o[qt2][0] = __builtin_amdgcn_mfma_f32_16x16x32_bf16(pa, bv[0][ks], o[qt2][0], 0, 0, 0);
        o[qt2][1] = __builtin_amdgcn_mfma_f32_16x16x32_bf16(pa, bv[1][ks], o[qt2][1], 0, 0, 0);
      }
    }
    u16* ob = out + (size_t)widx * 64 * 96 + head * 32;
#pragma unroll
    for (int qt2 = 0; qt2 < 2; qt2++)
#pragma unroll
      for (int jt = 0; jt < 2; jt++)
#pragma unroll
        for (int e = 0; e < 4; e++)
          ob[(size_t)(qh * 32 + qt2 * 16 + lhi * 4 + e) * 96 + jt * 16 + llo] =
              f2bf(o[qt2][jt][e]);
  }
}

// ---------------- fused proj + residual + LN2 + MLP + residual --------------
// Block = 128 natural rows, 4 waves x 32 rows (wave-private -> barrier-free).
// Phase P: proj GEMM (A from bb window-gathered, B from global bf16 W),
//   vv = acc + bias + shortcut(bx) kept in REGISTERS; LN2 -> LDS Xs (bf16).
// Phase M: fc1+GELU->Hs (LDS) ->fc2, chunk-interleaved; epilogue
//   bx = vv + mlp_out (single bx write; no intermediate HBM traffic).
__global__ __launch_bounds__(256, 2) void k_pm(const u16* __restrict__ X,
                                               const u16* __restrict__ Wp,
                                               const float* __restrict__ bp,
                                               const float* __restrict__ lng,
                                               const float* __restrict__ lnb,
                                               const u16* __restrict__ W1,
                                               const float* __restrict__ b1,
                                               const u16* __restrict__ W2,
                                               const float* __restrict__ b2,
                                               float* __restrict__ bx, int shifted) {
  __shared__ __align__(16) u16 Xs[128 * 104];   // LN2 output (A-frag source)
  __shared__ __align__(16) u16 Hs[128 * 104];   // MLP hidden chunk
  int tid = threadIdx.x;
  int wv = tid >> 6, lane = tid & 63;
  int llo = lane & 15, lhi = lane >> 4;
  int r0 = blockIdx.x << 7;
  int rowb = wv * 32;

  // shortcut prefetch (natural rows)
  float vv[2][4][6];
#pragma unroll
  for (int i = 0; i < 2; i++)
#pragma unroll
    for (int rg = 0; rg < 4; rg++) {
      int row = r0 + rowb + i * 16 + lhi * 4 + rg;
#pragma unroll
      for (int j = 0; j < 6; j++)
        vv[i][rg][j] = bx[(size_t)row * 96 + j * 16 + llo];
    }

  // proj A-frags (window-gathered rows from attention output)
  bf16x8 a[2][3];
#pragma unroll
  for (int i = 0; i < 2; i++) {
    int r = r0 + rowb + i * 16 + llo;
    int w = r & 63, h = (r >> 6) & 63, d = (r >> 12) & 31, bb = r >> 17;
    if (shifted) { d = (d + 30) & 31; h = (h + 62) & 63; w = (w + 62) & 63; }
    int widx = ((bb * 8 + (d >> 2)) * 16 + (h >> 2)) * 16 + (w >> 2);
    int rsrc = (widx << 6) + ((d & 3) << 4) + ((h & 3) << 2) + (w & 3);
#pragma unroll
    for (int ks = 0; ks < 3; ks++)
      a[i][ks] = *(const bf16x8*)(X + (size_t)rsrc * 96 + ks * 32 + lhi * 8);
  }

  // ---- phase P: proj GEMM ----
  {
    f32x4 acc[2][6];
#pragma unroll
    for (int i = 0; i < 2; i++)
#pragma unroll
      for (int j = 0; j < 6; j++) acc[i][j] = (f32x4){0.f, 0.f, 0.f, 0.f};
#pragma unroll
    for (int ks = 0; ks < 3; ks++) {
      bf16x8 b[6];
#pragma unroll
      for (int j = 0; j < 6; j++)
        b[j] = *(const bf16x8*)(Wp + (size_t)(j * 16 + llo) * 96 + ks * 32 + lhi * 8);
#pragma unroll
      for (int i = 0; i < 2; i++)
#pragma unroll
        for (int j = 0; j < 6; j++)
          acc[i][j] = __builtin_amdgcn_mfma_f32_16x16x32_bf16(a[i][ks], b[j], acc[i][j], 0, 0, 0);
    }

    // vv += proj + bias; LN2 -> Xs (bf16), vv stays in registers
    float bj[6], gj[6], betaj[6];
#pragma unroll
    for (int j = 0; j < 6; j++) {
      int col = j * 16 + llo;
      bj[j] = bp[col]; gj[j] = lng[col]; betaj[j] = lnb[col];
    }
#pragma unroll
    for (int i = 0; i < 2; i++) {
#pragma unroll
      for (int rg = 0; rg < 4; rg++) {
        int lrow = rowb + i * 16 + lhi * 4 + rg;
        float sum = 0.f;
#pragma unroll
        for (int j = 0; j < 6; j++) {
          vv[i][rg][j] += acc[i][j][rg] + bj[j];
          sum += vv[i][rg][j];
        }
#pragma unroll
        for (int m = 1; m <= 8; m <<= 1) sum += __shfl_xor(sum, m);
        float mean = sum * (1.f / 96.f);
        float vs = 0.f;
#pragma unroll
        for (int j = 0; j < 6; j++) { float dd = vv[i][rg][j] - mean; vs += dd * dd; }
#pragma unroll
        for (int m = 1; m <= 8; m <<= 1) vs += __shfl_xor(vs, m);
        float rstd = rsqrtf(vs * (1.f / 96.f) + 1e-5f);
#pragma unroll
        for (int j = 0; j < 6; j++)
          Xs[lrow * 104 + j * 16 + llo] =
              f2bf((vv[i][rg][j] - mean) * rstd * gj[j] + betaj[j]);
      }
    }
  }

  // ---- phase M: MLP (A-frags from Xs; same-wave LDS ordering, no barrier) --
  bf16x8 ax[2][3];
#pragma unroll
  for (int i = 0; i < 2; i++)
#pragma unroll
    for (int ks = 0; ks < 3; ks++)
      ax[i][ks] = *(const bf16x8*)&Xs[(rowb + i * 16 + llo) * 104 + ks * 32 + lhi * 8];

  f32x4 acc2[2][6];
#pragma unroll
  for (int i = 0; i < 2; i++)
#pragma unroll
    for (int j = 0; j < 6; j++) acc2[i][j] = (f32x4){0.f, 0.f, 0.f, 0.f};

  for (int c = 0; c < 4; c++) {
    f32x4 acc[2][6];
#pragma unroll
    for (int i = 0; i < 2; i++)
#pragma unroll
      for (int j = 0; j < 6; j++) acc[i][j] = (f32x4){0.f, 0.f, 0.f, 0.f};
#pragma unroll
    for (int ks = 0; ks < 3; ks++)
#pragma unroll
      for (int j = 0; j < 6; j++) {
        bf16x8 b = *(const bf16x8*)(W1 + (size_t)(c * 96 + j * 16 + llo) * 96 +
                                    ks * 32 + lhi * 8);
        acc[0][j] = __builtin_amdgcn_mfma_f32_16x16x32_bf16(ax[0][ks], b, acc[0][j], 0, 0, 0);
        acc[1][j] = __builtin_amdgcn_mfma_f32_16x16x32_bf16(ax[1][ks], b, acc[1][j], 0, 0, 0);
      }
#pragma unroll
    for (int j = 0; j < 6; j++) {
      float bb_ = b1[c * 96 + j * 16 + llo];
#pragma unroll
      for (int i = 0; i < 2; i++)
#pragma unroll
        for (int rg = 0; rg < 4; rg++)
          Hs[(rowb + i * 16 + lhi * 4 + rg) * 104 + j * 16 + llo] =
              f2bf(gelu_f(acc[i][j][rg] + bb_));
    }
    bf16x8 ah[2][3];
#pragma unroll
    for (int i = 0; i < 2; i++)
#pragma unroll
      for (int ks = 0; ks < 3; ks++)
        ah[i][ks] = *(const bf16x8*)&Hs[(rowb + i * 16 + llo) * 104 + ks * 32 + lhi * 8];
#pragma unroll
    for (int ks = 0; ks < 3; ks++)
#pragma unroll
      for (int j = 0; j < 6; j++) {
        bf16x8 b = *(const bf16x8*)(W2 + (size_t)(j * 16 + llo) * 384 + c * 96 +
                                    ks * 32 + lhi * 8);
        acc2[0][j] = __builtin_amdgcn_mfma_f32_16x16x32_bf16(ah[0][ks], b, acc2[0][j], 0, 0, 0);
        acc2[1][j] = __builtin_amdgcn_mfma_f32_16x16x32_bf16(ah[1][ks], b, acc2[1][j], 0, 0, 0);
      }
  }

  // epilogue: bx = vv + mlp_out + bias (single bx write)
#pragma unroll
  for (int i = 0; i < 2; i++)
#pragma unroll
    for (int j = 0; j < 6; j++) {
      float bb_ = b2[j * 16 + llo];
#pragma unroll
      for (int rg = 0; rg < 4; rg++) {
        size_t off = (size_t)(r0 + rowb + i * 16 + lhi * 4 + rg) * 96 + j * 16 + llo;
        bx[off] = vv[i][rg][j] + acc2[i][j][rg] + bb_;
      }
    }
}

// ---------------- launcher ----------------
extern "C" void kernel_launch(void* const* d_in, const int* in_sizes, int n_in,
                              void* d_out, int out_size, void* d_ws, size_t ws_size,
                              hipStream_t stream) {
  const float* x_in = (const float*)d_in[0];
  const float* n1g = (const float*)d_in[1];
  const float* n1b = (const float*)d_in[2];
  const float* qkvw = (const float*)d_in[3];
  const float* qkvb = (const float*)d_in[4];
  const float* rpb = (const float*)d_in[5];
  const float* projw = (const float*)d_in[6];
  const float* projb = (const float*)d_in[7];
  const float* n2g = (const float*)d_in[8];
  const float* n2b = (const float*)d_in[9];
  const float* fc1w = (const float*)d_in[10];
  const float* fc1b = (const float*)d_in[11];
  const float* fc2w = (const float*)d_in[12];
  const float* fc2b = (const float*)d_in[13];
  float* outp = (float*)d_out;

  // workspace: bx fp32 (100.7 MB) | bb bf16 (50.3) | bf16 weights
  char* ws = (char*)d_ws;
  float* bx = (float*)ws;
  u16* bb = (u16*)(ws + 100663296);       // attn out (bf16)
  u16* wq_bf = (u16*)(ws + 150994944);    // 2 x 288 x 96
  u16* wp_bf = wq_bf + 2 * 288 * 96;      // 2 x 96 x 96
  u16* w1_bf = wp_bf + 2 * 96 * 96;       // 2 x 384 x 96
  u16* w2_bf = w1_bf + 2 * 384 * 96;      // 2 x 96 x 384

  k_tin<<<dim3(kS / 32, 3, kB), dim3(32, 8), 0, stream>>>(x_in, bx);
  k_wcvt<<<dim3(72, 4), 256, 0, stream>>>(qkvw, projw, fc1w, fc2w,
                                          wq_bf, wp_bf, w1_bf, w2_bf);

  for (int blk = 0; blk < 2; blk++) {
    int sh = blk;  // block 1 is shifted
    k_qa<<<kM / 128, 1024, 0, stream>>>(bx, n1g + blk * 96, n1b + blk * 96,
                                        wq_bf + blk * 288 * 96, qkvb + blk * 288,
                                        rpb + blk * 343 * 3, bb, sh);
    k_pm<<<kM / 128, 256, 0, stream>>>(bb, wp_bf + blk * 96 * 96, projb + blk * 96,
                                       n2g + blk * 96, n2b + blk * 96,
                                       w1_bf + blk * 384 * 96, fc1b + blk * 384,
                                       w2_bf + blk * 96 * 384, fc2b + blk * 96,
                                       bx, sh);
  }

  k_tout<<<dim3(kS / 32, 3, kB), dim3(32, 8), 0, stream>>>(bx, outp);
}

// Round 13
// 684.050 us; speedup vs baseline: 1.4547x; 1.0643x over previous
//
#include <hip/hip_runtime.h>
#include <math.h>

typedef unsigned short u16;
typedef unsigned int u32;
#define DEVI __device__ __forceinline__

typedef __attribute__((ext_vector_type(8))) short bf16x8;
typedef __attribute__((ext_vector_type(4))) float f32x4;

// problem constants
constexpr int kB = 2, kC = 96, kD = 32, kH = 64, kW = 64;
constexpr int kS = kD * kH * kW;   // 131072 spatial positions per batch
constexpr int kM = kB * kS;        // 262144 total tokens
constexpr float kScale = 0.17677669529663687f;  // 32^-0.5

DEVI u16 f2bf(float f) {           // fp32 -> bf16 round-to-nearest-even
  u32 x = __float_as_uint(f);
  return (u16)((x + 0x7fffu + ((x >> 16) & 1u)) >> 16);
}
DEVI float bf2f(u16 v) { return __uint_as_float(((u32)v) << 16); }
DEVI u32 pack2(float a, float b) { return (u32)f2bf(a) | ((u32)f2bf(b) << 16); }

// exact-GELU via Abramowitz-Stegun 7.1.26 erf (|eps| <= 1.5e-7, << bf16 ulp)
DEVI float gelu_f(float v) {
  float x = v * 0.70710678118654752f;
  float ax = fabsf(x);
  float t = __builtin_amdgcn_rcpf(fmaf(0.3275911f, ax, 1.0f));
  float y = t * fmaf(t, fmaf(t, fmaf(t, fmaf(t, 1.061405429f, -1.453152027f),
                                     1.421413741f), -0.284496736f), 0.254829592f);
  float e = __expf(-x * x);
  float erfv = copysignf(fmaf(-y, e, 1.0f), x);
  return 0.5f * v * (1.0f + erfv);
}

// ---------------- transpose (B,C,S) -> (B,S,C) ----------------
__global__ void k_tin(const float* __restrict__ in, float* __restrict__ out) {
  __shared__ float tile[32][33];
  int s0 = blockIdx.x << 5, c0 = blockIdx.y << 5, b = blockIdx.z;
  int tx = threadIdx.x, ty = threadIdx.y;
#pragma unroll
  for (int q = 0; q < 4; q++)
    tile[ty + q * 8][tx] = in[((size_t)(b * kC + c0 + ty + q * 8)) * kS + s0 + tx];
  __syncthreads();
#pragma unroll
  for (int q = 0; q < 4; q++)
    out[((size_t)(b * kS + s0 + ty + q * 8)) * kC + c0 + tx] = tile[tx][ty + q * 8];
}

// ---------------- one-time weight fp32 -> bf16 conversion -------------------
__global__ __launch_bounds__(256) void k_wcvt(const float* __restrict__ q,
                                              const float* __restrict__ p,
                                              const float* __restrict__ f1,
                                              const float* __restrict__ f2,
                                              u16* dq, u16* dp, u16* df1, u16* df2) {
  int a = blockIdx.y;
  const float* sp; u16* dst; int n;
  if (a == 0)      { sp = q;  dst = dq;  n = 2 * 288 * 96; }
  else if (a == 1) { sp = p;  dst = dp;  n = 2 * 96 * 96; }
  else if (a == 2) { sp = f1; dst = df1; n = 2 * 384 * 96; }
  else             { sp = f2; dst = df2; n = 2 * 96 * 384; }
  for (int i = (blockIdx.x * 256 + threadIdx.x) * 4; i < n; i += gridDim.x * 1024) {
    float4 v = *(const float4*)(sp + i);
    *(u32*)(dst + i) = pack2(v.x, v.y);
    *(u32*)(dst + i + 2) = pack2(v.z, v.w);
  }
}

// ---------------- fused LN1 + QKV-GEMM + windowed attention (16 waves) ------
__global__ __launch_bounds__(1024, 4) void k_qa(const float* __restrict__ BX,
                                                const float* __restrict__ g1,
                                                const float* __restrict__ be1,
                                                const u16* __restrict__ Wq,
                                                const float* __restrict__ bq,
                                                const float* __restrict__ rpb,
                                                u16* __restrict__ out, int shifted) {
  __shared__ __align__(16) char arena[70720];
  u16* QK = (u16*)arena;                 // [128][200]: cols 0..95 Q, 96..191 K
  u16* VT = (u16*)(arena + 51200);       // [pair*3+head][32 d][40]: V^T
  float* RP = (float*)(arena + 66560);   // [3][343]

  int tid = threadIdx.x, wv = tid >> 6, lane = tid & 63;
  int llo = lane & 15, lhi = lane >> 4;
  int r0 = blockIdx.x << 7;
  int rowb = (wv >> 1) * 16;             // GEMM row base
  int colb = (wv & 1) * 48;              // GEMM col base

  for (int t = tid; t < 1029; t += 1024) {
    int head = t / 343, idx = t - head * 343;
    RP[t] = rpb[idx * 3 + head];
  }

  // ---- fused LN1: gather x row (window order -> natural), normalize ----
  {
    int r = r0 + rowb + llo;
    int wI = r >> 6, n = r & 63;
    int Xw = wI & 15, Xh = (wI >> 4) & 15, Xd = (wI >> 8) & 7, Xb = wI >> 11;
    int d = Xd * 4 + (n >> 4), h = Xh * 4 + ((n >> 2) & 3), w = Xw * 4 + (n & 3);
    if (shifted) { d = (d + 2) & 31; h = (h + 2) & 63; w = (w + 2) & 63; }
    const float* xr = BX + (size_t)(((Xb * kD + d) * kH + h) * kW + w) * 96;
    float xv[3][8];
#pragma unroll
    for (int ks = 0; ks < 3; ks++) {
      float4 p0 = *(const float4*)(xr + ks * 32 + lhi * 8);
      float4 p1 = *(const float4*)(xr + ks * 32 + lhi * 8 + 4);
      xv[ks][0] = p0.x; xv[ks][1] = p0.y; xv[ks][2] = p0.z; xv[ks][3] = p0.w;
      xv[ks][4] = p1.x; xv[ks][5] = p1.y; xv[ks][6] = p1.z; xv[ks][7] = p1.w;
    }
    float sum = 0.f;
#pragma unroll
    for (int ks = 0; ks < 3; ks++)
#pragma unroll
      for (int e = 0; e < 8; e++) sum += xv[ks][e];
    sum += __shfl_xor(sum, 16); sum += __shfl_xor(sum, 32);
    float mean = sum * (1.f / 96.f);
    float vs = 0.f;
#pragma unroll
    for (int ks = 0; ks < 3; ks++)
#pragma unroll
      for (int e = 0; e < 8; e++) { float dd = xv[ks][e] - mean; vs += dd * dd; }
    vs += __shfl_xor(vs, 16); vs += __shfl_xor(vs, 32);
    float rstd = rsqrtf(vs * (1.f / 96.f) + 1e-5f);
    bf16x8 a[3];
#pragma unroll
    for (int ks = 0; ks < 3; ks++) {
      const float* gp = g1 + ks * 32 + lhi * 8;
      const float* bp = be1 + ks * 32 + lhi * 8;
      float4 g0 = *(const float4*)gp, g4 = *(const float4*)(gp + 4);
      float4 b0 = *(const float4*)bp, b4 = *(const float4*)(bp + 4);
      float gf[8] = {g0.x, g0.y, g0.z, g0.w, g4.x, g4.y, g4.z, g4.w};
      float bf[8] = {b0.x, b0.y, b0.z, b0.w, b4.x, b4.y, b4.z, b4.w};
      bf16x8 t;
#pragma unroll
      for (int e = 0; e < 8; e++)
        t[e] = (short)f2bf((xv[ks][e] - mean) * rstd * gf[e] + bf[e]);
      a[ks] = t;
    }

    // ---- QKV GEMM: B-frags direct from global bf16 W, no barriers ----
    for (int c = 0; c < 3; c++) {
      f32x4 acc[3];
#pragma unroll
      for (int j = 0; j < 3; j++) acc[j] = (f32x4){0.f, 0.f, 0.f, 0.f};
#pragma unroll
      for (int ks = 0; ks < 3; ks++)
#pragma unroll
        for (int j = 0; j < 3; j++) {
          bf16x8 b = *(const bf16x8*)(Wq + (size_t)(c * 96 + colb + j * 16 + llo) * 96 +
                                      ks * 32 + lhi * 8);
          acc[j] = __builtin_amdgcn_mfma_f32_16x16x32_bf16(a[ks], b, acc[j], 0, 0, 0);
        }
      if (c < 2) {  // Q / K -> QK row-major
#pragma unroll
        for (int j = 0; j < 3; j++) {
          int col = colb + j * 16 + llo;
          float bb_ = bq[c * 96 + col];
#pragma unroll
          for (int rg = 0; rg < 4; rg++)
            QK[(rowb + lhi * 4 + rg) * 200 + c * 96 + col] = f2bf(acc[j][rg] + bb_);
        }
      } else {      // V -> VT transposed per (pair, head)
#pragma unroll
        for (int j = 0; j < 3; j++) {
          int dcol = colb + j * 16 + llo;
          float bb_ = bq[192 + dcol];
          int head = dcol >> 5, dd = dcol & 31;
#pragma unroll
          for (int rg = 0; rg < 4; rg++) {
            int row = rowb + lhi * 4 + rg;
            VT[(((row >> 6) * 3 + head) * 32 + dd) * 40 + (row & 63)] = f2bf(acc[j][rg] + bb_);
          }
        }
      }
    }
  }
  __syncthreads();

  // attention: 12 units = (pair, head, q-half); waves 12..15 idle
  int u = wv;
  bool active = (u < 12);
  int pair = u / 6, rem = u - pair * 6, head = rem >> 1, qh = rem & 1;
  int widx = (blockIdx.x << 1) + pair;
  int ww = widx & 15, wh = (widx >> 4) & 15, wd = (widx >> 8) & 7;
  const float* rp = RP + head * 343;
  const u16* qkw = QK + pair * 64 * 200;
  u16* plw = QK + u * 2112;              // P overlay on dead QK (32 x stride 66)

  f32x4 s[2][4];
  bf16x8 bv[2][2];
  if (active) {
    bf16x8 aq[2], bk[4];
#pragma unroll
    for (int qt2 = 0; qt2 < 2; qt2++)
      aq[qt2] = *(const bf16x8*)&qkw[(qh * 32 + qt2 * 16 + llo) * 200 + head * 32 + lhi * 8];
#pragma unroll
    for (int kt = 0; kt < 4; kt++)
      bk[kt] = *(const bf16x8*)&qkw[(kt * 16 + llo) * 200 + 96 + head * 32 + lhi * 8];
    const u16* vtb = VT + (pair * 3 + head) * 32 * 40;
#pragma unroll
    for (int jt = 0; jt < 2; jt++)
#pragma unroll
      for (int ks = 0; ks < 2; ks++)
        bv[jt][ks] = *(const bf16x8*)&vtb[(jt * 16 + llo) * 40 + ks * 32 + lhi * 8];

#pragma unroll
    for (int qt2 = 0; qt2 < 2; qt2++)
#pragma unroll
      for (int kt = 0; kt < 4; kt++)
        s[qt2][kt] = __builtin_amdgcn_mfma_f32_16x16x32_bf16(
            aq[qt2], bk[kt], (f32x4){0.f, 0.f, 0.f, 0.f}, 0, 0, 0);

    int jh = llo >> 2, jw = llo & 3;
    int mi_h = (wh == 15) ? (1 + (lhi >= 2)) : 0;
    int mj_hw = ((wh == 15) ? (1 + (jh >= 2)) : 0) * 3 +
                ((ww == 15) ? (1 + (jw >= 2)) : 0);
#pragma unroll
    for (int qt2 = 0; qt2 < 2; qt2++) {
      int qt = qh * 2 + qt2;
#pragma unroll
      for (int kt = 0; kt < 4; kt++) {
        const float* rb = &rp[(qt - kt + 3) * 49 + (lhi - jh + 3) * 7 + (3 - jw)];
#pragma unroll
        for (int e = 0; e < 4; e++) {
          float val = fmaf(s[qt2][kt][e], kScale, rb[e]);
          if (shifted) {
            int ci = ((wd == 7) ? (1 + (qt >= 2)) : 0) * 9 + mi_h * 3 +
                     ((ww == 15) ? (1 + (e >= 2)) : 0);
            int cj = ((wd == 7) ? (1 + (kt >= 2)) : 0) * 9 + mj_hw;
            if (ci != cj) val -= 100.f;
          }
          s[qt2][kt][e] = val;
        }
      }
    }
    // softmax per row (qt2, e): local max/sum over kt, butterfly over llo
#pragma unroll
    for (int qt2 = 0; qt2 < 2; qt2++) {
      f32x4 m;
#pragma unroll
      for (int e = 0; e < 4; e++)
        m[e] = fmaxf(fmaxf(s[qt2][0][e], s[qt2][1][e]), fmaxf(s[qt2][2][e], s[qt2][3][e]));
#pragma unroll
      for (int msk = 1; msk <= 8; msk <<= 1)
#pragma unroll
        for (int e = 0; e < 4; e++) m[e] = fmaxf(m[e], __shfl_xor(m[e], msk));
      f32x4 sum2 = (f32x4){0.f, 0.f, 0.f, 0.f};
#pragma unroll
      for (int kt = 0; kt < 4; kt++)
#pragma unroll
        for (int e = 0; e < 4; e++) {
          float p = __expf(s[qt2][kt][e] - m[e]);
          s[qt2][kt][e] = p;
          sum2[e] += p;
        }
#pragma unroll
      for (int msk = 1; msk <= 8; msk <<= 1)
#pragma unroll
        for (int e = 0; e < 4; e++) sum2[e] += __shfl_xor(sum2[e], msk);
#pragma unroll
      for (int e = 0; e < 4; e++) sum2[e] = 1.f / sum2[e];
#pragma unroll
      for (int kt = 0; kt < 4; kt++)
#pragma unroll
        for (int e = 0; e < 4; e++) s[qt2][kt][e] *= sum2[e];
    }
  }
  __syncthreads();  // all QK reads complete -> safe to overlay P
  if (active) {
#pragma unroll
    for (int qt2 = 0; qt2 < 2; qt2++)
#pragma unroll
      for (int kt = 0; kt < 4; kt++)
#pragma unroll
        for (int e = 0; e < 4; e++)
          plw[(qt2 * 16 + lhi * 4 + e) * 66 + kt * 16 + llo] = f2bf(s[qt2][kt][e]);
  }
  __syncthreads();
  if (active) {
    f32x4 o[2][2];
#pragma unroll
    for (int qt2 = 0; qt2 < 2; qt2++) {
      o[qt2][0] = (f32x4){0.f, 0.f, 0.f, 0.f};
      o[qt2][1] = (f32x4){0.f, 0.f, 0.f, 0.f};
#pragma unroll
      for (int ks = 0; ks < 2; ks++) {
        bf16x8 pa = *(const bf16x8*)&plw[(qt2 * 16 + llo) * 66 + ks * 32 + lhi * 8];
        o[qt2][0] = __builtin_amdgcn_mfma_f32_16x16x32_bf16(pa, bv[0][ks], o[qt2][0], 0, 0, 0);
        o[qt2][1] = __builtin_amdgcn_mfma_f32_16x16x32_bf16(pa, bv[1][ks], o[qt2][1], 0, 0, 0);
      }
    }
    u16* ob = out + (size_t)widx * 64 * 96 + head * 32;
#pragma unroll
    for (int qt2 = 0; qt2 < 2; qt2++)
#pragma unroll
      for (int jt = 0; jt < 2; jt++)
#pragma unroll
        for (int e = 0; e < 4; e++)
          ob[(size_t)(qh * 32 + qt2 * 16 + lhi * 4 + e) * 96 + jt * 16 + llo] =
              f2bf(o[qt2][jt][e]);
  }
}

// ---------------- fused proj + residual + LN2 + MLP (+ output transpose) ----
// Block = 128 natural rows, 4 waves x 32 wave-private rows. Every cross-lane
// LDS hand-off is fenced with __syncthreads() (race fix for r12: same-wave
// ds_write -> ds_read ordering is NOT guaranteed without a fence; TBAA on the
// float/u16 overlay makes it worse). Regions are wave-private so barriers are
// pure fences. TOUT=1: final x routed through fp32 LDS tile and written
// CHANNEL-MAJOR directly (deletes the separate k_tout pass).
template <int TOUT>
__global__ __launch_bounds__(256, 3) void k_pm(const u16* __restrict__ X,
                                               const u16* __restrict__ Wp,
                                               const float* __restrict__ bp,
                                               const float* __restrict__ lng,
                                               const float* __restrict__ lnb,
                                               const u16* __restrict__ W1,
                                               const float* __restrict__ b1,
                                               const u16* __restrict__ W2,
                                               const float* __restrict__ b2,
                                               float* __restrict__ bx,
                                               float* __restrict__ outd, int shifted) {
  __shared__ __align__(16) char arena[53248];
  u16* Xs = (u16*)arena;             // [128][104] LN2 out (A-frag source)
  u16* Hs = (u16*)(arena + 26624);   // [128][104] hidden chunk
  float* Lo = (float*)arena;         // [wave][32][98] fp32 out tile (overlay)

  int tid = threadIdx.x, wv = tid >> 6, lane = tid & 63;
  int llo = lane & 15, lhi = lane >> 4;
  int r0 = blockIdx.x << 7;
  int rowb = wv * 32;

  // shortcut prefetch (natural rows)
  float vv[2][4][6];
#pragma unroll
  for (int i = 0; i < 2; i++)
#pragma unroll
    for (int rg = 0; rg < 4; rg++) {
      int row = r0 + rowb + i * 16 + lhi * 4 + rg;
#pragma unroll
      for (int j = 0; j < 6; j++)
        vv[i][rg][j] = bx[(size_t)row * 96 + j * 16 + llo];
    }

  // proj A-frags (window-gathered rows from attention output)
  bf16x8 a[2][3];
#pragma unroll
  for (int i = 0; i < 2; i++) {
    int r = r0 + rowb + i * 16 + llo;
    int w = r & 63, h = (r >> 6) & 63, d = (r >> 12) & 31, bb = r >> 17;
    if (shifted) { d = (d + 30) & 31; h = (h + 62) & 63; w = (w + 62) & 63; }
    int widx = ((bb * 8 + (d >> 2)) * 16 + (h >> 2)) * 16 + (w >> 2);
    int rsrc = (widx << 6) + ((d & 3) << 4) + ((h & 3) << 2) + (w & 3);
#pragma unroll
    for (int ks = 0; ks < 3; ks++)
      a[i][ks] = *(const bf16x8*)(X + (size_t)rsrc * 96 + ks * 32 + lhi * 8);
  }

  // ---- phase P: proj GEMM ----
  {
    f32x4 acc[2][6];
#pragma unroll
    for (int i = 0; i < 2; i++)
#pragma unroll
      for (int j = 0; j < 6; j++) acc[i][j] = (f32x4){0.f, 0.f, 0.f, 0.f};
#pragma unroll
    for (int ks = 0; ks < 3; ks++) {
      bf16x8 b[6];
#pragma unroll
      for (int j = 0; j < 6; j++)
        b[j] = *(const bf16x8*)(Wp + (size_t)(j * 16 + llo) * 96 + ks * 32 + lhi * 8);
#pragma unroll
      for (int i = 0; i < 2; i++)
#pragma unroll
        for (int j = 0; j < 6; j++)
          acc[i][j] = __builtin_amdgcn_mfma_f32_16x16x32_bf16(a[i][ks], b[j], acc[i][j], 0, 0, 0);
    }

    // vv += proj + bias; LN2 -> Xs (bf16), vv stays in registers
    float bj[6], gj[6], betaj[6];
#pragma unroll
    for (int j = 0; j < 6; j++) {
      int col = j * 16 + llo;
      bj[j] = bp[col]; gj[j] = lng[col]; betaj[j] = lnb[col];
    }
#pragma unroll
    for (int i = 0; i < 2; i++) {
#pragma unroll
      for (int rg = 0; rg < 4; rg++) {
        int lrow = rowb + i * 16 + lhi * 4 + rg;
        float sum = 0.f;
#pragma unroll
        for (int j = 0; j < 6; j++) {
          vv[i][rg][j] += acc[i][j][rg] + bj[j];
          sum += vv[i][rg][j];
        }
#pragma unroll
        for (int m = 1; m <= 8; m <<= 1) sum += __shfl_xor(sum, m);
        float mean = sum * (1.f / 96.f);
        float vs = 0.f;
#pragma unroll
        for (int j = 0; j < 6; j++) { float dd = vv[i][rg][j] - mean; vs += dd * dd; }
#pragma unroll
        for (int m = 1; m <= 8; m <<= 1) vs += __shfl_xor(vs, m);
        float rstd = rsqrtf(vs * (1.f / 96.f) + 1e-5f);
#pragma unroll
        for (int j = 0; j < 6; j++)
          Xs[lrow * 104 + j * 16 + llo] =
              f2bf((vv[i][rg][j] - mean) * rstd * gj[j] + betaj[j]);
      }
    }
  }
  __syncthreads();  // fence: Xs writes -> cross-lane ax reads

  // ---- phase M: MLP ----
  bf16x8 ax[2][3];
#pragma unroll
  for (int i = 0; i < 2; i++)
#pragma unroll
    for (int ks = 0; ks < 3; ks++)
      ax[i][ks] = *(const bf16x8*)&Xs[(rowb + i * 16 + llo) * 104 + ks * 32 + lhi * 8];

  f32x4 acc2[2][6];
#pragma unroll
  for (int i = 0; i < 2; i++)
#pragma unroll
    for (int j = 0; j < 6; j++) acc2[i][j] = (f32x4){0.f, 0.f, 0.f, 0.f};

  for (int c = 0; c < 4; c++) {
    f32x4 acc[2][6];
#pragma unroll
    for (int i = 0; i < 2; i++)
#pragma unroll
      for (int j = 0; j < 6; j++) acc[i][j] = (f32x4){0.f, 0.f, 0.f, 0.f};
#pragma unroll
    for (int ks = 0; ks < 3; ks++)
#pragma unroll
      for (int j = 0; j < 6; j++) {
        bf16x8 b = *(const bf16x8*)(W1 + (size_t)(c * 96 + j * 16 + llo) * 96 +
                                    ks * 32 + lhi * 8);
        acc[0][j] = __builtin_amdgcn_mfma_f32_16x16x32_bf16(ax[0][ks], b, acc[0][j], 0, 0, 0);
        acc[1][j] = __builtin_amdgcn_mfma_f32_16x16x32_bf16(ax[1][ks], b, acc[1][j], 0, 0, 0);
      }
#pragma unroll
    for (int j = 0; j < 6; j++) {
      float bb_ = b1[c * 96 + j * 16 + llo];
#pragma unroll
      for (int i = 0; i < 2; i++)
#pragma unroll
        for (int rg = 0; rg < 4; rg++)
          Hs[(rowb + i * 16 + lhi * 4 + rg) * 104 + j * 16 + llo] =
              f2bf(gelu_f(acc[i][j][rg] + bb_));
    }
    __syncthreads();  // fence: Hs writes -> cross-lane ah reads
    bf16x8 ah[2][3];
#pragma unroll
    for (int i = 0; i < 2; i++)
#pragma unroll
      for (int ks = 0; ks < 3; ks++)
        ah[i][ks] = *(const bf16x8*)&Hs[(rowb + i * 16 + llo) * 104 + ks * 32 + lhi * 8];
#pragma unroll
    for (int ks = 0; ks < 3; ks++)
#pragma unroll
      for (int j = 0; j < 6; j++) {
        bf16x8 b = *(const bf16x8*)(W2 + (size_t)(j * 16 + llo) * 384 + c * 96 +
                                    ks * 32 + lhi * 8);
        acc2[0][j] = __builtin_amdgcn_mfma_f32_16x16x32_bf16(ah[0][ks], b, acc2[0][j], 0, 0, 0);
        acc2[1][j] = __builtin_amdgcn_mfma_f32_16x16x32_bf16(ah[1][ks], b, acc2[1][j], 0, 0, 0);
      }
    __syncthreads();  // fence: ah reads -> next chunk's Hs writes
  }

  if (TOUT == 0) {
    // epilogue: bx = vv + mlp_out + bias (single bx write)
#pragma unroll
    for (int i = 0; i < 2; i++)
#pragma unroll
      for (int j = 0; j < 6; j++) {
        float bb_ = b2[j * 16 + llo];
#pragma unroll
        for (int rg = 0; rg < 4; rg++) {
          size_t off = (size_t)(r0 + rowb + i * 16 + lhi * 4 + rg) * 96 + j * 16 + llo;
          bx[off] = vv[i][rg][j] + acc2[i][j][rg] + bb_;
        }
      }
  } else {
    // epilogue: route through per-wave fp32 LDS tile (overlay on dead Xs/Hs)
    // and write CHANNEL-MAJOR output directly (deletes k_tout).
    float* LoW = Lo + wv * 32 * 98;
#pragma unroll
    for (int i = 0; i < 2; i++)
#pragma unroll
      for (int j = 0; j < 6; j++) {
        float bb_ = b2[j * 16 + llo];
#pragma unroll
        for (int rg = 0; rg < 4; rg++)
          LoW[(i * 16 + lhi * 4 + rg) * 98 + j * 16 + llo] =
              vv[i][rg][j] + acc2[i][j][rg] + bb_;
      }
    __syncthreads();  // fence: Lo writes -> cross-lane Lo reads
    int b = r0 >> 17;                    // blocks never straddle batches
    int sbase = (r0 + rowb) & (kS - 1);
    int ss = lane & 31, ch = lane >> 5;  // lane -> (s offset, channel parity)
#pragma unroll
    for (int c2 = 0; c2 < 48; c2++) {
      int c = c2 * 2 + ch;
      outd[((size_t)(b * kC + c)) * kS + sbase + ss] = LoW[ss * 98 + c];
    }
  }
}

// ---------------- launcher ----------------
extern "C" void kernel_launch(void* const* d_in, const int* in_sizes, int n_in,
                              void* d_out, int out_size, void* d_ws, size_t ws_size,
                              hipStream_t stream) {
  const float* x_in = (const float*)d_in[0];
  const float* n1g = (const float*)d_in[1];
  const float* n1b = (const float*)d_in[2];
  const float* qkvw = (const float*)d_in[3];
  const float* qkvb = (const float*)d_in[4];
  const float* rpb = (const float*)d_in[5];
  const float* projw = (const float*)d_in[6];
  const float* projb = (const float*)d_in[7];
  const float* n2g = (const float*)d_in[8];
  const float* n2b = (const float*)d_in[9];
  const float* fc1w = (const float*)d_in[10];
  const float* fc1b = (const float*)d_in[11];
  const float* fc2w = (const float*)d_in[12];
  const float* fc2b = (const float*)d_in[13];
  float* outp = (float*)d_out;

  // workspace: bx fp32 (100.7 MB) | bb bf16 (50.3) | bf16 weights
  char* ws = (char*)d_ws;
  float* bx = (float*)ws;
  u16* bb = (u16*)(ws + 100663296);       // attn out (bf16)
  u16* wq_bf = (u16*)(ws + 150994944);    // 2 x 288 x 96
  u16* wp_bf = wq_bf + 2 * 288 * 96;      // 2 x 96 x 96
  u16* w1_bf = wp_bf + 2 * 96 * 96;       // 2 x 384 x 96
  u16* w2_bf = w1_bf + 2 * 384 * 96;      // 2 x 96 x 384

  k_tin<<<dim3(kS / 32, 3, kB), dim3(32, 8), 0, stream>>>(x_in, bx);
  k_wcvt<<<dim3(72, 4), 256, 0, stream>>>(qkvw, projw, fc1w, fc2w,
                                          wq_bf, wp_bf, w1_bf, w2_bf);

  // block 0 (unshifted)
  k_qa<<<kM / 128, 1024, 0, stream>>>(bx, n1g, n1b, wq_bf, qkvb,
                                      rpb, bb, 0);
  k_pm<0><<<kM / 128, 256, 0, stream>>>(bb, wp_bf, projb, n2g, n2b,
                                        w1_bf, fc1b, w2_bf, fc2b, bx, nullptr, 0);
  // block 1 (shifted) — k_pm writes channel-major output directly
  k_qa<<<kM / 128, 1024, 0, stream>>>(bx, n1g + 96, n1b + 96, wq_bf + 288 * 96,
                                      qkvb + 288, rpb + 343 * 3, bb, 1);
  k_pm<1><<<kM / 128, 256, 0, stream>>>(bb, wp_bf + 96 * 96, projb + 96,
                                        n2g + 96, n2b + 96, w1_bf + 384 * 96,
                                        fc1b + 384, w2_bf + 96 * 384, fc2b + 96,
                                        bx, outp, 1);
}